// Round 2
// baseline (216.381 us; speedup 1.0000x reference)
//
#include <hip/hip_runtime.h>
#include <hip/hip_bf16.h>
#include <cmath>

#define Bb 2
#define Tt 2048
#define Dd 512
#define Hh 8
#define Cc 64
#define WINw 128

using u16x8 = __attribute__((ext_vector_type(8))) unsigned short;
using s16x8 = __attribute__((ext_vector_type(8))) short;
using f32x4 = __attribute__((ext_vector_type(4))) float;

__device__ __forceinline__ float bf2f(unsigned short u) {
  union { unsigned int i; float f; } v; v.i = ((unsigned int)u) << 16; return v.f;
}
__device__ __forceinline__ unsigned short f2bf(float f) {
  __hip_bfloat16 b = __float2bfloat16(f);
  return *reinterpret_cast<unsigned short*>(&b);
}

// ------- weight transpose + f32->bf16: dst[n][k] = bf16(src[k][n]), 512x512 -
__global__ __launch_bounds__(256) void transpose512(
    const float* __restrict__ src, unsigned short* __restrict__ dst) {
  __shared__ unsigned short tile[64 * 65];
  int n0 = blockIdx.x * 64, k0 = blockIdx.y * 64;
  int tx = threadIdx.x, ty = threadIdx.y;  // (64,4)
  #pragma unroll
  for (int i = 0; i < 16; ++i) {
    int k = ty * 16 + i;
    tile[k * 65 + tx] = f2bf(src[(k0 + k) * 512 + n0 + tx]);
  }
  __syncthreads();
  #pragma unroll
  for (int i = 0; i < 16; ++i) {
    int n = ty * 16 + i;
    dst[(n0 + n) * 512 + k0 + tx] = tile[tx * 65 + n];
  }
}

// ---------------- QKV projection GEMM + fused RMSNorm + RoPE ----------------
// C-tile 64x64: M-tile = 64 rows of h (b*T+t), N-tile = one head (64 ch).
// Wave w computes rows [w*16, w*16+16). mfma_f32_16x16x32_bf16.
// A-frag: A[m=lane&15][k=quad*8+j]; B-frag: B[k=quad*8+j][n=lane&15];
// C/D: row=quad*4+reg, col=lane&15  (verified layouts, guide §3).
__global__ __launch_bounds__(256) void qkv_gemm(
    const float* __restrict__ Hm,          // (4096,512) f32 row-major
    const unsigned short* __restrict__ WT, // (512,512) bf16 [n][k]
    const float* __restrict__ normw,       // (64) f32  (unused if !do_rope)
    const float* __restrict__ rcos,        // (2048,64) f32
    const float* __restrict__ rsin,        // (2048,64) f32
    unsigned short* __restrict__ Out,      // (B,H,T,C) bf16
    int do_rope) {
  __shared__ alignas(16) unsigned short Al[64 * 72];
  __shared__ alignas(16) unsigned short Bl[64 * 72];
  int m0 = blockIdx.x * 64;
  int head = blockIdx.y;
  int n0 = head * 64;
  int tid = threadIdx.x;
  int wave = tid >> 6, lane = tid & 63;
  int ln = lane & 15, qd = lane >> 4;
  int lrow = tid >> 2;            // 0..63
  int lcol = (tid & 3) * 16;      // 0,16,32,48

  f32x4 acc[4] = {f32x4{0,0,0,0}, f32x4{0,0,0,0}, f32x4{0,0,0,0}, f32x4{0,0,0,0}};

  for (int k0 = 0; k0 < 512; k0 += 64) {
    const float4* ga = (const float4*)&Hm[(m0 + lrow) * 512 + k0 + lcol];
    float4 f0 = ga[0], f1 = ga[1], f2 = ga[2], f3 = ga[3];
    const u16x8* gb = (const u16x8*)&WT[(n0 + lrow) * 512 + k0 + lcol];
    u16x8 b0 = gb[0], b1 = gb[1];
    u16x8 c0 = {f2bf(f0.x), f2bf(f0.y), f2bf(f0.z), f2bf(f0.w),
                f2bf(f1.x), f2bf(f1.y), f2bf(f1.z), f2bf(f1.w)};
    u16x8 c1 = {f2bf(f2.x), f2bf(f2.y), f2bf(f2.z), f2bf(f2.w),
                f2bf(f3.x), f2bf(f3.y), f2bf(f3.z), f2bf(f3.w)};
    *(u16x8*)&Al[lrow * 72 + lcol] = c0;
    *(u16x8*)&Al[lrow * 72 + lcol + 8] = c1;
    *(u16x8*)&Bl[lrow * 72 + lcol] = b0;
    *(u16x8*)&Bl[lrow * 72 + lcol + 8] = b1;
    __syncthreads();
    #pragma unroll
    for (int kk = 0; kk < 64; kk += 32) {
      s16x8 af = *(const s16x8*)&Al[(wave * 16 + ln) * 72 + kk + qd * 8];
      #pragma unroll
      for (int nt = 0; nt < 4; ++nt) {
        s16x8 bfm = *(const s16x8*)&Bl[(nt * 16 + ln) * 72 + kk + qd * 8];
        acc[nt] = __builtin_amdgcn_mfma_f32_16x16x32_bf16(af, bfm, acc[nt], 0, 0, 0);
      }
    }
    __syncthreads();
  }

  float vals[4][4];
  #pragma unroll
  for (int nt = 0; nt < 4; ++nt)
    #pragma unroll
    for (int r = 0; r < 4; ++r) vals[nt][r] = acc[nt][r];

  if (do_rope) {
    // RMSNorm per row (16-lane group reduction; xor<16 stays within group)
    #pragma unroll
    for (int r = 0; r < 4; ++r) {
      float ss = 0.f;
      #pragma unroll
      for (int nt = 0; nt < 4; ++nt) ss += vals[nt][r] * vals[nt][r];
      ss += __shfl_xor(ss, 1, 64);
      ss += __shfl_xor(ss, 2, 64);
      ss += __shfl_xor(ss, 4, 64);
      ss += __shfl_xor(ss, 8, 64);
      float nrm = rsqrtf(ss * (1.0f / 64.0f) + 1e-6f);
      #pragma unroll
      for (int nt = 0; nt < 4; ++nt) vals[nt][r] *= nrm;
    }
    #pragma unroll
    for (int nt = 0; nt < 4; ++nt) {
      float w = normw[nt * 16 + ln];
      #pragma unroll
      for (int r = 0; r < 4; ++r) vals[nt][r] *= w;
    }
    // RoPE: partner channel c^32 lives in acc-set nt^2, same lane
    float res[4][4];
    #pragma unroll
    for (int r = 0; r < 4; ++r) {
      int row = m0 + wave * 16 + qd * 4 + r;
      int t = row & (Tt - 1);
      #pragma unroll
      for (int nt = 0; nt < 4; ++nt) {
        int c = nt * 16 + ln;
        float cs = rcos[t * 64 + c];
        float sn = rsin[t * 64 + c];
        float part = vals[nt ^ 2][r];
        float rot = (nt < 2) ? -part : part;
        res[nt][r] = vals[nt][r] * cs + rot * sn;
      }
    }
    #pragma unroll
    for (int nt = 0; nt < 4; ++nt)
      #pragma unroll
      for (int r = 0; r < 4; ++r) vals[nt][r] = res[nt][r];
  }

  #pragma unroll
  for (int r = 0; r < 4; ++r) {
    int row = m0 + wave * 16 + qd * 4 + r;
    int b = row >> 11, t = row & (Tt - 1);
    unsigned short* op = &Out[((b * Hh + head) * Tt + t) * 64 + ln];
    #pragma unroll
    for (int nt = 0; nt < 4; ++nt) op[nt * 16] = f2bf(vals[nt][r]);
  }
}

// ---------------- sliding-window attention: one wave per query --------------
__global__ __launch_bounds__(256) void attn_kernel(
    const unsigned short* __restrict__ Q,  // (B,H,T,C) bf16
    const unsigned short* __restrict__ K,
    const unsigned short* __restrict__ V,
    unsigned short* __restrict__ AO) {     // (B,T,H,C) bf16
  int tid = threadIdx.x;
  int wave = tid >> 6, lane = tid & 63;
  int wg = blockIdx.x * 4 + wave;          // 0..32767 = (b*H+h)*T + t
  int t = wg & (Tt - 1);
  int bh = wg >> 11;
  int b = bh >> 3, h = bh & 7;

  const unsigned short* Qp = Q + (bh * Tt + t) * 64;
  float qv = bf2f(Qp[lane]);

  int key0 = t - 127 + lane;
  int key1 = key0 + 64;
  const unsigned short* Kb = K + bh * Tt * 64;
  const u16x8* kr0 = (const u16x8*)&Kb[(key0 > 0 ? key0 : 0) * 64];
  const u16x8* kr1 = (const u16x8*)&Kb[(key1 > 0 ? key1 : 0) * 64];
  u16x8 k0v[8], k1v[8];
  #pragma unroll
  for (int i = 0; i < 8; ++i) { k0v[i] = kr0[i]; k1v[i] = kr1[i]; }

  float d0 = 0.f, d1 = 0.f;
  #pragma unroll
  for (int c = 0; c < 64; ++c) {
    float qc = __shfl(qv, c, 64);
    d0 += qc * bf2f(k0v[c >> 3][c & 7]);
    d1 += qc * bf2f(k1v[c >> 3][c & 7]);
  }
  float s0 = (key0 >= 0) ? d0 * 0.125f : -INFINITY;
  float s1 = (key1 >= 0) ? d1 * 0.125f : -INFINITY;

  float mx = fmaxf(s0, s1);
  #pragma unroll
  for (int off = 32; off > 0; off >>= 1) mx = fmaxf(mx, __shfl_xor(mx, off, 64));
  float e0 = __expf(s0 - mx), e1 = __expf(s1 - mx);
  float sm = e0 + e1;
  #pragma unroll
  for (int off = 32; off > 0; off >>= 1) sm += __shfl_xor(sm, off, 64);
  float inv = 1.0f / sm;
  float p0 = e0 * inv, p1 = e1 * inv;

  const unsigned short* Vb = V + bh * Tt * 64 + lane;
  float o = 0.f;
  #pragma unroll
  for (int j = 0; j < 64; ++j) {
    int key = t - 127 + j;
    o += __shfl(p0, j, 64) * bf2f(Vb[(key > 0 ? key : 0) * 64]);
  }
  #pragma unroll
  for (int j = 0; j < 64; ++j) {
    int key = t - 63 + j;
    o += __shfl(p1, j, 64) * bf2f(Vb[(key > 0 ? key : 0) * 64]);
  }
  AO[((b * Tt + t) * Hh + h) * 64 + lane] = f2bf(o);
}

// ---------------- output GEMM: AO (4096,512) @ W_o -> out (f32) -------------
__global__ __launch_bounds__(256) void out_gemm(
    const unsigned short* __restrict__ Am,  // (4096,512) bf16 = (B,T,H*C)
    const unsigned short* __restrict__ WT,  // W_o^T bf16 [n][k]
    float* __restrict__ Out) {              // (4096,512) f32
  __shared__ alignas(16) unsigned short Al[64 * 72];
  __shared__ alignas(16) unsigned short Bl[64 * 72];
  int m0 = blockIdx.x * 64;
  int n0 = blockIdx.y * 64;
  int tid = threadIdx.x;
  int wave = tid >> 6, lane = tid & 63;
  int ln = lane & 15, qd = lane >> 4;
  int lrow = tid >> 2;
  int lcol = (tid & 3) * 16;

  f32x4 acc[4] = {f32x4{0,0,0,0}, f32x4{0,0,0,0}, f32x4{0,0,0,0}, f32x4{0,0,0,0}};

  for (int k0 = 0; k0 < 512; k0 += 64) {
    const u16x8* ga = (const u16x8*)&Am[(m0 + lrow) * 512 + k0 + lcol];
    u16x8 a0 = ga[0], a1 = ga[1];
    const u16x8* gb = (const u16x8*)&WT[(n0 + lrow) * 512 + k0 + lcol];
    u16x8 b0 = gb[0], b1 = gb[1];
    *(u16x8*)&Al[lrow * 72 + lcol] = a0;
    *(u16x8*)&Al[lrow * 72 + lcol + 8] = a1;
    *(u16x8*)&Bl[lrow * 72 + lcol] = b0;
    *(u16x8*)&Bl[lrow * 72 + lcol + 8] = b1;
    __syncthreads();
    #pragma unroll
    for (int kk = 0; kk < 64; kk += 32) {
      s16x8 af = *(const s16x8*)&Al[(wave * 16 + ln) * 72 + kk + qd * 8];
      #pragma unroll
      for (int nt = 0; nt < 4; ++nt) {
        s16x8 bfm = *(const s16x8*)&Bl[(nt * 16 + ln) * 72 + kk + qd * 8];
        acc[nt] = __builtin_amdgcn_mfma_f32_16x16x32_bf16(af, bfm, acc[nt], 0, 0, 0);
      }
    }
    __syncthreads();
  }

  #pragma unroll
  for (int r = 0; r < 4; ++r) {
    int row = m0 + wave * 16 + qd * 4 + r;
    #pragma unroll
    for (int nt = 0; nt < 4; ++nt)
      Out[row * 512 + n0 + nt * 16 + ln] = acc[nt][r];
  }
}

extern "C" void kernel_launch(void* const* d_in, const int* in_sizes, int n_in,
                              void* d_out, int out_size, void* d_ws, size_t ws_size,
                              hipStream_t stream) {
  const float* h   = (const float*)d_in[0];
  const float* rc  = (const float*)d_in[1];
  const float* rs  = (const float*)d_in[2];
  const float* Wq  = (const float*)d_in[3];
  const float* Wk  = (const float*)d_in[4];
  const float* Wv  = (const float*)d_in[5];
  const float* Wo  = (const float*)d_in[6];
  const float* qnw = (const float*)d_in[7];
  const float* knw = (const float*)d_in[8];

  unsigned short* ws  = (unsigned short*)d_ws;
  unsigned short* WTq = ws;
  unsigned short* WTk = WTq + 512 * 512;
  unsigned short* WTv = WTk + 512 * 512;
  unsigned short* WTo = WTv + 512 * 512;
  unsigned short* Qw  = WTo + 512 * 512;
  unsigned short* Kw  = Qw + 2097152;
  unsigned short* Vw  = Kw + 2097152;
  unsigned short* AOw = Vw + 2097152;

  dim3 tb(64, 4);
  transpose512<<<dim3(8, 8), tb, 0, stream>>>(Wq, WTq);
  transpose512<<<dim3(8, 8), tb, 0, stream>>>(Wk, WTk);
  transpose512<<<dim3(8, 8), tb, 0, stream>>>(Wv, WTv);
  transpose512<<<dim3(8, 8), tb, 0, stream>>>(Wo, WTo);

  qkv_gemm<<<dim3(64, 8), 256, 0, stream>>>(h, WTq, qnw, rc, rs, Qw, 1);
  qkv_gemm<<<dim3(64, 8), 256, 0, stream>>>(h, WTk, knw, rc, rs, Kw, 1);
  qkv_gemm<<<dim3(64, 8), 256, 0, stream>>>(h, WTv, nullptr, nullptr, nullptr, Vw, 0);

  attn_kernel<<<8192, 256, 0, stream>>>(Qw, Kw, Vw, AOw);

  out_gemm<<<dim3(64, 8), 256, 0, stream>>>(AOw, WTo, (float*)d_out);
}

// Round 3
// 131.126 us; speedup vs baseline: 1.6502x; 1.6502x over previous
//
#include <hip/hip_runtime.h>
#include <hip/hip_bf16.h>
#include <cmath>

#define Bb 2
#define Tt 2048
#define Dd 512
#define Hh 8
#define Cc 64
#define WINw 128

using u16x8 = __attribute__((ext_vector_type(8))) unsigned short;
using s16x8 = __attribute__((ext_vector_type(8))) short;
using f32x4 = __attribute__((ext_vector_type(4))) float;

__device__ __forceinline__ float bf2f(unsigned short u) {
  union { unsigned int i; float f; } v; v.i = ((unsigned int)u) << 16; return v.f;
}
__device__ __forceinline__ unsigned short f2bf(float f) {
  __hip_bfloat16 b = __float2bfloat16(f);
  return *reinterpret_cast<unsigned short*>(&b);
}

// ------- weight transpose + f32->bf16: dst[n][k] = bf16(src[k][n]), 512x512 -
__global__ __launch_bounds__(256) void transpose512(
    const float* __restrict__ src, unsigned short* __restrict__ dst) {
  __shared__ unsigned short tile[64 * 65];
  int n0 = blockIdx.x * 64, k0 = blockIdx.y * 64;
  int tx = threadIdx.x, ty = threadIdx.y;  // (64,4)
  #pragma unroll
  for (int i = 0; i < 16; ++i) {
    int k = ty * 16 + i;
    tile[k * 65 + tx] = f2bf(src[(k0 + k) * 512 + n0 + tx]);
  }
  __syncthreads();
  #pragma unroll
  for (int i = 0; i < 16; ++i) {
    int n = ty * 16 + i;
    dst[(n0 + n) * 512 + k0 + tx] = tile[tx * 65 + n];
  }
}

// ---------------- QKV projection GEMM + fused RMSNorm + RoPE ----------------
__global__ __launch_bounds__(256) void qkv_gemm(
    const float* __restrict__ Hm,          // (4096,512) f32 row-major
    const unsigned short* __restrict__ WT, // (512,512) bf16 [n][k]
    const float* __restrict__ normw,       // (64) f32  (unused if !do_rope)
    const float* __restrict__ rcos,        // (2048,64) f32
    const float* __restrict__ rsin,        // (2048,64) f32
    unsigned short* __restrict__ Out,      // (B,H,T,C) bf16
    int do_rope) {
  __shared__ alignas(16) unsigned short Al[64 * 72];
  __shared__ alignas(16) unsigned short Bl[64 * 72];
  int m0 = blockIdx.x * 64;
  int head = blockIdx.y;
  int n0 = head * 64;
  int tid = threadIdx.x;
  int wave = tid >> 6, lane = tid & 63;
  int ln = lane & 15, qd = lane >> 4;
  int lrow = tid >> 2;            // 0..63
  int lcol = (tid & 3) * 16;      // 0,16,32,48

  f32x4 acc[4] = {f32x4{0,0,0,0}, f32x4{0,0,0,0}, f32x4{0,0,0,0}, f32x4{0,0,0,0}};

  for (int k0 = 0; k0 < 512; k0 += 64) {
    const float4* ga = (const float4*)&Hm[(m0 + lrow) * 512 + k0 + lcol];
    float4 f0 = ga[0], f1 = ga[1], f2 = ga[2], f3 = ga[3];
    const u16x8* gb = (const u16x8*)&WT[(n0 + lrow) * 512 + k0 + lcol];
    u16x8 b0 = gb[0], b1 = gb[1];
    u16x8 c0 = {f2bf(f0.x), f2bf(f0.y), f2bf(f0.z), f2bf(f0.w),
                f2bf(f1.x), f2bf(f1.y), f2bf(f1.z), f2bf(f1.w)};
    u16x8 c1 = {f2bf(f2.x), f2bf(f2.y), f2bf(f2.z), f2bf(f2.w),
                f2bf(f3.x), f2bf(f3.y), f2bf(f3.z), f2bf(f3.w)};
    *(u16x8*)&Al[lrow * 72 + lcol] = c0;
    *(u16x8*)&Al[lrow * 72 + lcol + 8] = c1;
    *(u16x8*)&Bl[lrow * 72 + lcol] = b0;
    *(u16x8*)&Bl[lrow * 72 + lcol + 8] = b1;
    __syncthreads();
    #pragma unroll
    for (int kk = 0; kk < 64; kk += 32) {
      s16x8 af = *(const s16x8*)&Al[(wave * 16 + ln) * 72 + kk + qd * 8];
      #pragma unroll
      for (int nt = 0; nt < 4; ++nt) {
        s16x8 bfm = *(const s16x8*)&Bl[(nt * 16 + ln) * 72 + kk + qd * 8];
        acc[nt] = __builtin_amdgcn_mfma_f32_16x16x32_bf16(af, bfm, acc[nt], 0, 0, 0);
      }
    }
    __syncthreads();
  }

  float vals[4][4];
  #pragma unroll
  for (int nt = 0; nt < 4; ++nt)
    #pragma unroll
    for (int r = 0; r < 4; ++r) vals[nt][r] = acc[nt][r];

  if (do_rope) {
    #pragma unroll
    for (int r = 0; r < 4; ++r) {
      float ss = 0.f;
      #pragma unroll
      for (int nt = 0; nt < 4; ++nt) ss += vals[nt][r] * vals[nt][r];
      ss += __shfl_xor(ss, 1, 64);
      ss += __shfl_xor(ss, 2, 64);
      ss += __shfl_xor(ss, 4, 64);
      ss += __shfl_xor(ss, 8, 64);
      float nrm = rsqrtf(ss * (1.0f / 64.0f) + 1e-6f);
      #pragma unroll
      for (int nt = 0; nt < 4; ++nt) vals[nt][r] *= nrm;
    }
    #pragma unroll
    for (int nt = 0; nt < 4; ++nt) {
      float w = normw[nt * 16 + ln];
      #pragma unroll
      for (int r = 0; r < 4; ++r) vals[nt][r] *= w;
    }
    float res[4][4];
    #pragma unroll
    for (int r = 0; r < 4; ++r) {
      int row = m0 + wave * 16 + qd * 4 + r;
      int t = row & (Tt - 1);
      #pragma unroll
      for (int nt = 0; nt < 4; ++nt) {
        int c = nt * 16 + ln;
        float cs = rcos[t * 64 + c];
        float sn = rsin[t * 64 + c];
        float part = vals[nt ^ 2][r];
        float rot = (nt < 2) ? -part : part;
        res[nt][r] = vals[nt][r] * cs + rot * sn;
      }
    }
    #pragma unroll
    for (int nt = 0; nt < 4; ++nt)
      #pragma unroll
      for (int r = 0; r < 4; ++r) vals[nt][r] = res[nt][r];
  }

  #pragma unroll
  for (int r = 0; r < 4; ++r) {
    int row = m0 + wave * 16 + qd * 4 + r;
    int b = row >> 11, t = row & (Tt - 1);
    unsigned short* op = &Out[((b * Hh + head) * Tt + t) * 64 + ln];
    #pragma unroll
    for (int nt = 0; nt < 4; ++nt) op[nt * 16] = f2bf(vals[nt][r]);
  }
}

// ---------- MFMA sliding-window attention: 64 queries / block ---------------
// Block = (qtile, bh). Queries t0..t0+63; keys kb..kb+191, kb = t0-128.
// Wave w owns queries q0=w*16..+15. S = Q K^T via mfma (m=q,n=kk,k=c);
// softmax in regs (row lives in 16-lane group); P -> LDS (reuse K buf);
// O = P V via mfma (m=q,n=c,k=kk) against V^T staged in LDS.
__global__ __launch_bounds__(256) void attn_mfma(
    const unsigned short* __restrict__ Q,  // (B,H,T,C) bf16
    const unsigned short* __restrict__ K,
    const unsigned short* __restrict__ V,
    unsigned short* __restrict__ AO) {     // (B,T,H,C) bf16
  __shared__ alignas(16) unsigned short Ql[64 * 72];
  __shared__ alignas(16) unsigned short KP[192 * 72];  // K tile; then P[64][200]
  __shared__ alignas(16) unsigned short Vt[64 * 200];  // V^T: [c][kk]

  int tid = threadIdx.x;
  int wave = tid >> 6, lane = tid & 63;
  int ln = lane & 15, qd = lane >> 4;
  int qtile = blockIdx.x, bh = blockIdx.y;
  int t0 = qtile * 64;
  int kb = t0 - 128;

  const unsigned short* Qg = Q + ((size_t)bh * Tt + t0) * 64;
  const unsigned short* Kg = K + (size_t)bh * Tt * 64;
  const unsigned short* Vg = V + (size_t)bh * Tt * 64;

  int srow = tid >> 2;          // 0..63
  int scol = (tid & 3) * 16;    // 0,16,32,48

  // stage Q
  {
    const u16x8* g = (const u16x8*)&Qg[srow * 64 + scol];
    u16x8 a0 = g[0], a1 = g[1];
    *(u16x8*)&Ql[srow * 72 + scol] = a0;
    *(u16x8*)&Ql[srow * 72 + scol + 8] = a1;
  }
  // stage K (row-major, pad 72) and V (transposed into Vt)
  #pragma unroll
  for (int p = 0; p < 3; ++p) {
    int row = p * 64 + srow;            // 0..191
    int kg = kb + row; if (kg < 0) kg = 0;
    const u16x8* gk = (const u16x8*)&Kg[kg * 64 + scol];
    u16x8 k0 = gk[0], k1 = gk[1];
    const u16x8* gv = (const u16x8*)&Vg[kg * 64 + scol];
    u16x8 v0 = gv[0], v1 = gv[1];
    *(u16x8*)&KP[row * 72 + scol] = k0;
    *(u16x8*)&KP[row * 72 + scol + 8] = k1;
    #pragma unroll
    for (int j = 0; j < 8; ++j) {
      Vt[(scol + j) * 200 + row] = v0[j];
      Vt[(scol + 8 + j) * 200 + row] = v1[j];
    }
  }
  __syncthreads();

  // ---- S = Q K^T (16 q x 192 kk per wave) ----
  int q0 = wave * 16;
  s16x8 aq0 = *(const s16x8*)&Ql[(q0 + ln) * 72 + qd * 8];
  s16x8 aq1 = *(const s16x8*)&Ql[(q0 + ln) * 72 + 32 + qd * 8];
  f32x4 sf[12];
  #pragma unroll
  for (int nt = 0; nt < 12; ++nt) {
    s16x8 b0 = *(const s16x8*)&KP[(nt * 16 + ln) * 72 + qd * 8];
    s16x8 b1 = *(const s16x8*)&KP[(nt * 16 + ln) * 72 + 32 + qd * 8];
    f32x4 acc = {0.f, 0.f, 0.f, 0.f};
    acc = __builtin_amdgcn_mfma_f32_16x16x32_bf16(aq0, b0, acc, 0, 0, 0);
    acc = __builtin_amdgcn_mfma_f32_16x16x32_bf16(aq1, b1, acc, 0, 0, 0);
    sf[nt] = acc;
  }
  __syncthreads();  // all waves done reading KP: safe to reuse as P

  // ---- mask + softmax (row = q0 + qd*4 + r, cols nt*16+ln) ----
  unsigned short* Pl = KP;   // P[64][200]
  int ok0 = (t0 < 128) ? (128 - t0) : 0;  // kk >= ok0 <=> key index >= 0
  #pragma unroll
  for (int r = 0; r < 4; ++r) {
    int lq = q0 + qd * 4 + r;
    float mx = -INFINITY;
    #pragma unroll
    for (int nt = 0; nt < 12; ++nt) {
      int kk = nt * 16 + ln;
      bool valid = (kk > lq) && (kk <= lq + 128) && (kk >= ok0);
      float s = valid ? sf[nt][r] * 0.125f : -INFINITY;
      sf[nt][r] = s;
      mx = fmaxf(mx, s);
    }
    mx = fmaxf(mx, __shfl_xor(mx, 1, 64));
    mx = fmaxf(mx, __shfl_xor(mx, 2, 64));
    mx = fmaxf(mx, __shfl_xor(mx, 4, 64));
    mx = fmaxf(mx, __shfl_xor(mx, 8, 64));
    float sum = 0.f;
    #pragma unroll
    for (int nt = 0; nt < 12; ++nt) {
      float e = __expf(sf[nt][r] - mx);
      sf[nt][r] = e;
      sum += e;
    }
    sum += __shfl_xor(sum, 1, 64);
    sum += __shfl_xor(sum, 2, 64);
    sum += __shfl_xor(sum, 4, 64);
    sum += __shfl_xor(sum, 8, 64);
    float inv = 1.0f / sum;
    #pragma unroll
    for (int nt = 0; nt < 12; ++nt)
      Pl[lq * 200 + nt * 16 + ln] = f2bf(sf[nt][r] * inv);
  }
  __syncthreads();

  // ---- O = P V (16 q x 64 c per wave), k = 192 ----
  f32x4 oa[4] = {f32x4{0,0,0,0}, f32x4{0,0,0,0}, f32x4{0,0,0,0}, f32x4{0,0,0,0}};
  #pragma unroll
  for (int s = 0; s < 6; ++s) {
    s16x8 ap = *(const s16x8*)&Pl[(q0 + ln) * 200 + s * 32 + qd * 8];
    #pragma unroll
    for (int nt = 0; nt < 4; ++nt) {
      s16x8 bv = *(const s16x8*)&Vt[(nt * 16 + ln) * 200 + s * 32 + qd * 8];
      oa[nt] = __builtin_amdgcn_mfma_f32_16x16x32_bf16(ap, bv, oa[nt], 0, 0, 0);
    }
  }

  int b = bh >> 3, h = bh & 7;
  #pragma unroll
  for (int r = 0; r < 4; ++r) {
    int t = t0 + q0 + qd * 4 + r;
    unsigned short* op = &AO[(((size_t)b * Tt + t) * Hh + h) * 64 + ln];
    #pragma unroll
    for (int nt = 0; nt < 4; ++nt) op[nt * 16] = f2bf(oa[nt][r]);
  }
}

// ---------------- output GEMM: AO (4096,512) @ W_o -> out (f32) -------------
__global__ __launch_bounds__(256) void out_gemm(
    const unsigned short* __restrict__ Am,  // (4096,512) bf16 = (B,T,H*C)
    const unsigned short* __restrict__ WT,  // W_o^T bf16 [n][k]
    float* __restrict__ Out) {              // (4096,512) f32
  __shared__ alignas(16) unsigned short Al[64 * 72];
  __shared__ alignas(16) unsigned short Bl[64 * 72];
  int m0 = blockIdx.x * 64;
  int n0 = blockIdx.y * 64;
  int tid = threadIdx.x;
  int wave = tid >> 6, lane = tid & 63;
  int ln = lane & 15, qd = lane >> 4;
  int lrow = tid >> 2;
  int lcol = (tid & 3) * 16;

  f32x4 acc[4] = {f32x4{0,0,0,0}, f32x4{0,0,0,0}, f32x4{0,0,0,0}, f32x4{0,0,0,0}};

  for (int k0 = 0; k0 < 512; k0 += 64) {
    const u16x8* ga = (const u16x8*)&Am[(m0 + lrow) * 512 + k0 + lcol];
    u16x8 a0 = ga[0], a1 = ga[1];
    const u16x8* gb = (const u16x8*)&WT[(n0 + lrow) * 512 + k0 + lcol];
    u16x8 b0 = gb[0], b1 = gb[1];
    *(u16x8*)&Al[lrow * 72 + lcol] = a0;
    *(u16x8*)&Al[lrow * 72 + lcol + 8] = a1;
    *(u16x8*)&Bl[lrow * 72 + lcol] = b0;
    *(u16x8*)&Bl[lrow * 72 + lcol + 8] = b1;
    __syncthreads();
    #pragma unroll
    for (int kk = 0; kk < 64; kk += 32) {
      s16x8 af = *(const s16x8*)&Al[(wave * 16 + ln) * 72 + kk + qd * 8];
      #pragma unroll
      for (int nt = 0; nt < 4; ++nt) {
        s16x8 bfm = *(const s16x8*)&Bl[(nt * 16 + ln) * 72 + kk + qd * 8];
        acc[nt] = __builtin_amdgcn_mfma_f32_16x16x32_bf16(af, bfm, acc[nt], 0, 0, 0);
      }
    }
    __syncthreads();
  }

  #pragma unroll
  for (int r = 0; r < 4; ++r) {
    int row = m0 + wave * 16 + qd * 4 + r;
    #pragma unroll
    for (int nt = 0; nt < 4; ++nt)
      Out[row * 512 + n0 + nt * 16 + ln] = acc[nt][r];
  }
}

extern "C" void kernel_launch(void* const* d_in, const int* in_sizes, int n_in,
                              void* d_out, int out_size, void* d_ws, size_t ws_size,
                              hipStream_t stream) {
  const float* h   = (const float*)d_in[0];
  const float* rc  = (const float*)d_in[1];
  const float* rs  = (const float*)d_in[2];
  const float* Wq  = (const float*)d_in[3];
  const float* Wk  = (const float*)d_in[4];
  const float* Wv  = (const float*)d_in[5];
  const float* Wo  = (const float*)d_in[6];
  const float* qnw = (const float*)d_in[7];
  const float* knw = (const float*)d_in[8];

  unsigned short* ws  = (unsigned short*)d_ws;
  unsigned short* WTq = ws;
  unsigned short* WTk = WTq + 512 * 512;
  unsigned short* WTv = WTk + 512 * 512;
  unsigned short* WTo = WTv + 512 * 512;
  unsigned short* Qw  = WTo + 512 * 512;
  unsigned short* Kw  = Qw + 2097152;
  unsigned short* Vw  = Kw + 2097152;
  unsigned short* AOw = Vw + 2097152;

  dim3 tb(64, 4);
  transpose512<<<dim3(8, 8), tb, 0, stream>>>(Wq, WTq);
  transpose512<<<dim3(8, 8), tb, 0, stream>>>(Wk, WTk);
  transpose512<<<dim3(8, 8), tb, 0, stream>>>(Wv, WTv);
  transpose512<<<dim3(8, 8), tb, 0, stream>>>(Wo, WTo);

  qkv_gemm<<<dim3(64, 8), 256, 0, stream>>>(h, WTq, qnw, rc, rs, Qw, 1);
  qkv_gemm<<<dim3(64, 8), 256, 0, stream>>>(h, WTk, knw, rc, rs, Kw, 1);
  qkv_gemm<<<dim3(64, 8), 256, 0, stream>>>(h, WTv, nullptr, nullptr, nullptr, Vw, 0);

  attn_mfma<<<dim3(32, 16), 256, 0, stream>>>(Qw, Kw, Vw, AOw);

  out_gemm<<<dim3(64, 8), 256, 0, stream>>>(AOw, WTo, (float*)d_out);
}

// Round 4
// 116.909 us; speedup vs baseline: 1.8509x; 1.1216x over previous
//
#include <hip/hip_runtime.h>
#include <hip/hip_bf16.h>
#include <cmath>

#define Bb 2
#define Tt 2048
#define Dd 512
#define Hh 8
#define Cc 64
#define WINw 128

using u16x8 = __attribute__((ext_vector_type(8))) unsigned short;
using s16x8 = __attribute__((ext_vector_type(8))) short;
using f32x4 = __attribute__((ext_vector_type(4))) float;

__device__ __forceinline__ float bf2f(unsigned short u) {
  union { unsigned int i; float f; } v; v.i = ((unsigned int)u) << 16; return v.f;
}
__device__ __forceinline__ unsigned short f2bf(float f) {
  __hip_bfloat16 b = __float2bfloat16(f);
  return *reinterpret_cast<unsigned short*>(&b);
}

// ---------------- h: f32 -> bf16, 2M elements ------------------------------
__global__ __launch_bounds__(256) void cvt_f32_bf16(
    const float* __restrict__ src, unsigned short* __restrict__ dst) {
  size_t i = ((size_t)blockIdx.x * 256 + threadIdx.x) * 8;
  const float4* g = (const float4*)&src[i];
  float4 f0 = g[0], f1 = g[1];
  u16x8 o = {f2bf(f0.x), f2bf(f0.y), f2bf(f0.z), f2bf(f0.w),
             f2bf(f1.x), f2bf(f1.y), f2bf(f1.z), f2bf(f1.w)};
  *(u16x8*)&dst[i] = o;
}

// ------- all 4 weight transposes in one dispatch: dst[n][k]=bf16(src[k][n]) -
__global__ __launch_bounds__(256) void transpose_all(
    const float* __restrict__ s0, const float* __restrict__ s1,
    const float* __restrict__ s2, const float* __restrict__ s3,
    unsigned short* __restrict__ d) {   // 4 matrices contiguous, 512*512 each
  __shared__ unsigned short tile[64 * 65];
  const float* srcs[4] = {s0, s1, s2, s3};
  const float* src = srcs[blockIdx.z];
  unsigned short* dst = d + (size_t)blockIdx.z * 512 * 512;
  int n0 = blockIdx.x * 64, k0 = blockIdx.y * 64;
  int tx = threadIdx.x, ty = threadIdx.y;  // (64,4)
  #pragma unroll
  for (int i = 0; i < 16; ++i) {
    int k = ty * 16 + i;
    tile[k * 65 + tx] = f2bf(src[(k0 + k) * 512 + n0 + tx]);
  }
  __syncthreads();
  #pragma unroll
  for (int i = 0; i < 16; ++i) {
    int n = ty * 16 + i;
    dst[(n0 + n) * 512 + k0 + tx] = tile[tx * 65 + n];
  }
}

// ---------------- fused QKV GEMM (128x128 tile) + RMSNorm + RoPE ------------
// A = Hb (4096,512) bf16; B = WTall (1536,512) bf16 [n][k].
// Block tile: 128 M-rows x 128 N-cols (= 2 heads). 4 waves in 2x2;
// wave (wm,wn) computes 64x64 via acc[4][4] of 16x16x32 MFMAs.
__global__ __launch_bounds__(256) void qkv_fused(
    const unsigned short* __restrict__ Hb,
    const unsigned short* __restrict__ WTall,
    const float* __restrict__ qnw, const float* __restrict__ knw,
    const float* __restrict__ rcos, const float* __restrict__ rsin,
    unsigned short* __restrict__ Qw, unsigned short* __restrict__ Kw,
    unsigned short* __restrict__ Vw) {
  __shared__ alignas(16) unsigned short Al[128 * 72];
  __shared__ alignas(16) unsigned short Bl[128 * 72];
  int m0 = blockIdx.x * 128;
  int n0 = blockIdx.y * 128;
  int tid = threadIdx.x;
  int wave = tid >> 6, lane = tid & 63;
  int ln = lane & 15, qd = lane >> 4;
  int wm = wave >> 1, wn = wave & 1;
  int srow = tid >> 2, scol = (tid & 3) * 16;

  f32x4 acc[4][4];
  #pragma unroll
  for (int mi = 0; mi < 4; ++mi)
    #pragma unroll
    for (int ni = 0; ni < 4; ++ni) acc[mi][ni] = f32x4{0.f, 0.f, 0.f, 0.f};

  for (int k0 = 0; k0 < 512; k0 += 64) {
    #pragma unroll
    for (int p = 0; p < 2; ++p) {
      int row = p * 64 + srow;
      const u16x8* ga = (const u16x8*)&Hb[(size_t)(m0 + row) * 512 + k0 + scol];
      u16x8 a0 = ga[0], a1 = ga[1];
      const u16x8* gb = (const u16x8*)&WTall[(size_t)(n0 + row) * 512 + k0 + scol];
      u16x8 b0 = gb[0], b1 = gb[1];
      *(u16x8*)&Al[row * 72 + scol] = a0;
      *(u16x8*)&Al[row * 72 + scol + 8] = a1;
      *(u16x8*)&Bl[row * 72 + scol] = b0;
      *(u16x8*)&Bl[row * 72 + scol + 8] = b1;
    }
    __syncthreads();
    #pragma unroll
    for (int kk = 0; kk < 64; kk += 32) {
      s16x8 af[4], bfr[4];
      #pragma unroll
      for (int mi = 0; mi < 4; ++mi)
        af[mi] = *(const s16x8*)&Al[(wm * 64 + mi * 16 + ln) * 72 + kk + qd * 8];
      #pragma unroll
      for (int ni = 0; ni < 4; ++ni)
        bfr[ni] = *(const s16x8*)&Bl[(wn * 64 + ni * 16 + ln) * 72 + kk + qd * 8];
      #pragma unroll
      for (int mi = 0; mi < 4; ++mi)
        #pragma unroll
        for (int ni = 0; ni < 4; ++ni)
          acc[mi][ni] = __builtin_amdgcn_mfma_f32_16x16x32_bf16(
              af[mi], bfr[ni], acc[mi][ni], 0, 0, 0);
    }
    __syncthreads();
  }

  // epilogue: wave-uniform head
  int gh = blockIdx.y * 2 + wn;          // 0..23
  int mat = gh >> 3, head = gh & 7;
  unsigned short* Out = (mat == 0) ? Qw : (mat == 1) ? Kw : Vw;
  const float* nw = (mat == 0) ? qnw : knw;
  bool do_rope = (mat < 2);

  #pragma unroll
  for (int mi = 0; mi < 4; ++mi) {
    float vals[4][4];  // [ni][r]
    #pragma unroll
    for (int ni = 0; ni < 4; ++ni)
      #pragma unroll
      for (int r = 0; r < 4; ++r) vals[ni][r] = acc[mi][ni][r];

    if (do_rope) {
      #pragma unroll
      for (int r = 0; r < 4; ++r) {
        float ss = 0.f;
        #pragma unroll
        for (int ni = 0; ni < 4; ++ni) ss += vals[ni][r] * vals[ni][r];
        ss += __shfl_xor(ss, 1, 64);
        ss += __shfl_xor(ss, 2, 64);
        ss += __shfl_xor(ss, 4, 64);
        ss += __shfl_xor(ss, 8, 64);
        float nrm = rsqrtf(ss * (1.0f / 64.0f) + 1e-6f);
        #pragma unroll
        for (int ni = 0; ni < 4; ++ni) vals[ni][r] *= nrm;
      }
      #pragma unroll
      for (int ni = 0; ni < 4; ++ni) {
        float w = nw[ni * 16 + ln];
        #pragma unroll
        for (int r = 0; r < 4; ++r) vals[ni][r] *= w;
      }
      float res[4][4];
      #pragma unroll
      for (int r = 0; r < 4; ++r) {
        int row = m0 + wm * 64 + mi * 16 + qd * 4 + r;
        int t = row & (Tt - 1);
        #pragma unroll
        for (int ni = 0; ni < 4; ++ni) {
          int c = ni * 16 + ln;
          float cs = rcos[t * 64 + c];
          float sn = rsin[t * 64 + c];
          float part = vals[ni ^ 2][r];
          float rot = (ni < 2) ? -part : part;
          res[ni][r] = vals[ni][r] * cs + rot * sn;
        }
      }
      #pragma unroll
      for (int ni = 0; ni < 4; ++ni)
        #pragma unroll
        for (int r = 0; r < 4; ++r) vals[ni][r] = res[ni][r];
    }

    #pragma unroll
    for (int r = 0; r < 4; ++r) {
      int row = m0 + wm * 64 + mi * 16 + qd * 4 + r;
      int b = row >> 11, t = row & (Tt - 1);
      unsigned short* op = &Out[(((size_t)b * Hh + head) * Tt + t) * 64 + ln];
      #pragma unroll
      for (int ni = 0; ni < 4; ++ni) op[ni * 16] = f2bf(vals[ni][r]);
    }
  }
}

// ---------- MFMA sliding-window attention: 64 queries / block ---------------
__global__ __launch_bounds__(256) void attn_mfma(
    const unsigned short* __restrict__ Q,  // (B,H,T,C) bf16
    const unsigned short* __restrict__ K,
    const unsigned short* __restrict__ V,
    unsigned short* __restrict__ AO) {     // (B,T,H,C) bf16
  __shared__ alignas(16) unsigned short Ql[64 * 72];
  __shared__ alignas(16) unsigned short KP[192 * 72];  // K tile; then P[64][200]
  __shared__ alignas(16) unsigned short Vt[64 * 200];  // V^T: [c][kk]

  int tid = threadIdx.x;
  int wave = tid >> 6, lane = tid & 63;
  int ln = lane & 15, qd = lane >> 4;
  int qtile = blockIdx.x, bh = blockIdx.y;
  int t0 = qtile * 64;
  int kb = t0 - 128;

  const unsigned short* Qg = Q + ((size_t)bh * Tt + t0) * 64;
  const unsigned short* Kg = K + (size_t)bh * Tt * 64;
  const unsigned short* Vg = V + (size_t)bh * Tt * 64;

  int srow = tid >> 2;
  int scol = (tid & 3) * 16;

  {
    const u16x8* g = (const u16x8*)&Qg[srow * 64 + scol];
    u16x8 a0 = g[0], a1 = g[1];
    *(u16x8*)&Ql[srow * 72 + scol] = a0;
    *(u16x8*)&Ql[srow * 72 + scol + 8] = a1;
  }
  #pragma unroll
  for (int p = 0; p < 3; ++p) {
    int row = p * 64 + srow;            // 0..191
    int kg = kb + row; if (kg < 0) kg = 0;
    const u16x8* gk = (const u16x8*)&Kg[kg * 64 + scol];
    u16x8 k0 = gk[0], k1 = gk[1];
    const u16x8* gv = (const u16x8*)&Vg[kg * 64 + scol];
    u16x8 v0 = gv[0], v1 = gv[1];
    *(u16x8*)&KP[row * 72 + scol] = k0;
    *(u16x8*)&KP[row * 72 + scol + 8] = k1;
    #pragma unroll
    for (int j = 0; j < 8; ++j) {
      Vt[(scol + j) * 200 + row] = v0[j];
      Vt[(scol + 8 + j) * 200 + row] = v1[j];
    }
  }
  __syncthreads();

  int q0 = wave * 16;
  s16x8 aq0 = *(const s16x8*)&Ql[(q0 + ln) * 72 + qd * 8];
  s16x8 aq1 = *(const s16x8*)&Ql[(q0 + ln) * 72 + 32 + qd * 8];
  f32x4 sf[12];
  #pragma unroll
  for (int nt = 0; nt < 12; ++nt) {
    s16x8 b0 = *(const s16x8*)&KP[(nt * 16 + ln) * 72 + qd * 8];
    s16x8 b1 = *(const s16x8*)&KP[(nt * 16 + ln) * 72 + 32 + qd * 8];
    f32x4 acc = {0.f, 0.f, 0.f, 0.f};
    acc = __builtin_amdgcn_mfma_f32_16x16x32_bf16(aq0, b0, acc, 0, 0, 0);
    acc = __builtin_amdgcn_mfma_f32_16x16x32_bf16(aq1, b1, acc, 0, 0, 0);
    sf[nt] = acc;
  }
  __syncthreads();

  unsigned short* Pl = KP;
  int ok0 = (t0 < 128) ? (128 - t0) : 0;
  #pragma unroll
  for (int r = 0; r < 4; ++r) {
    int lq = q0 + qd * 4 + r;
    float mx = -INFINITY;
    #pragma unroll
    for (int nt = 0; nt < 12; ++nt) {
      int kk = nt * 16 + ln;
      bool valid = (kk > lq) && (kk <= lq + 128) && (kk >= ok0);
      float s = valid ? sf[nt][r] * 0.125f : -INFINITY;
      sf[nt][r] = s;
      mx = fmaxf(mx, s);
    }
    mx = fmaxf(mx, __shfl_xor(mx, 1, 64));
    mx = fmaxf(mx, __shfl_xor(mx, 2, 64));
    mx = fmaxf(mx, __shfl_xor(mx, 4, 64));
    mx = fmaxf(mx, __shfl_xor(mx, 8, 64));
    float sum = 0.f;
    #pragma unroll
    for (int nt = 0; nt < 12; ++nt) {
      float e = __expf(sf[nt][r] - mx);
      sf[nt][r] = e;
      sum += e;
    }
    sum += __shfl_xor(sum, 1, 64);
    sum += __shfl_xor(sum, 2, 64);
    sum += __shfl_xor(sum, 4, 64);
    sum += __shfl_xor(sum, 8, 64);
    float inv = 1.0f / sum;
    #pragma unroll
    for (int nt = 0; nt < 12; ++nt)
      Pl[lq * 200 + nt * 16 + ln] = f2bf(sf[nt][r] * inv);
  }
  __syncthreads();

  f32x4 oa[4] = {f32x4{0,0,0,0}, f32x4{0,0,0,0}, f32x4{0,0,0,0}, f32x4{0,0,0,0}};
  #pragma unroll
  for (int s = 0; s < 6; ++s) {
    s16x8 ap = *(const s16x8*)&Pl[(q0 + ln) * 200 + s * 32 + qd * 8];
    #pragma unroll
    for (int nt = 0; nt < 4; ++nt) {
      s16x8 bv = *(const s16x8*)&Vt[(nt * 16 + ln) * 200 + s * 32 + qd * 8];
      oa[nt] = __builtin_amdgcn_mfma_f32_16x16x32_bf16(ap, bv, oa[nt], 0, 0, 0);
    }
  }

  int b = bh >> 3, h = bh & 7;
  #pragma unroll
  for (int r = 0; r < 4; ++r) {
    int t = t0 + q0 + qd * 4 + r;
    unsigned short* op = &AO[(((size_t)b * Tt + t) * Hh + h) * 64 + ln];
    #pragma unroll
    for (int nt = 0; nt < 4; ++nt) op[nt * 16] = f2bf(oa[nt][r]);
  }
}

// ------------- output GEMM (128x128 tile): AO @ W_o -> out (f32) ------------
__global__ __launch_bounds__(256) void out_gemm128(
    const unsigned short* __restrict__ Am,  // (4096,512) bf16
    const unsigned short* __restrict__ WT,  // (512,512) bf16 [n][k]
    float* __restrict__ Out) {              // (4096,512) f32
  __shared__ alignas(16) unsigned short Al[128 * 72];
  __shared__ alignas(16) unsigned short Bl[128 * 72];
  int m0 = blockIdx.x * 128;
  int n0 = blockIdx.y * 128;
  int tid = threadIdx.x;
  int wave = tid >> 6, lane = tid & 63;
  int ln = lane & 15, qd = lane >> 4;
  int wm = wave >> 1, wn = wave & 1;
  int srow = tid >> 2, scol = (tid & 3) * 16;

  f32x4 acc[4][4];
  #pragma unroll
  for (int mi = 0; mi < 4; ++mi)
    #pragma unroll
    for (int ni = 0; ni < 4; ++ni) acc[mi][ni] = f32x4{0.f, 0.f, 0.f, 0.f};

  for (int k0 = 0; k0 < 512; k0 += 64) {
    #pragma unroll
    for (int p = 0; p < 2; ++p) {
      int row = p * 64 + srow;
      const u16x8* ga = (const u16x8*)&Am[(size_t)(m0 + row) * 512 + k0 + scol];
      u16x8 a0 = ga[0], a1 = ga[1];
      const u16x8* gb = (const u16x8*)&WT[(size_t)(n0 + row) * 512 + k0 + scol];
      u16x8 b0 = gb[0], b1 = gb[1];
      *(u16x8*)&Al[row * 72 + scol] = a0;
      *(u16x8*)&Al[row * 72 + scol + 8] = a1;
      *(u16x8*)&Bl[row * 72 + scol] = b0;
      *(u16x8*)&Bl[row * 72 + scol + 8] = b1;
    }
    __syncthreads();
    #pragma unroll
    for (int kk = 0; kk < 64; kk += 32) {
      s16x8 af[4], bfr[4];
      #pragma unroll
      for (int mi = 0; mi < 4; ++mi)
        af[mi] = *(const s16x8*)&Al[(wm * 64 + mi * 16 + ln) * 72 + kk + qd * 8];
      #pragma unroll
      for (int ni = 0; ni < 4; ++ni)
        bfr[ni] = *(const s16x8*)&Bl[(wn * 64 + ni * 16 + ln) * 72 + kk + qd * 8];
      #pragma unroll
      for (int mi = 0; mi < 4; ++mi)
        #pragma unroll
        for (int ni = 0; ni < 4; ++ni)
          acc[mi][ni] = __builtin_amdgcn_mfma_f32_16x16x32_bf16(
              af[mi], bfr[ni], acc[mi][ni], 0, 0, 0);
    }
    __syncthreads();
  }

  #pragma unroll
  for (int mi = 0; mi < 4; ++mi)
    #pragma unroll
    for (int r = 0; r < 4; ++r) {
      int row = m0 + wm * 64 + mi * 16 + qd * 4 + r;
      #pragma unroll
      for (int ni = 0; ni < 4; ++ni)
        Out[(size_t)row * 512 + n0 + wn * 64 + ni * 16 + ln] = acc[mi][ni][r];
    }
}

extern "C" void kernel_launch(void* const* d_in, const int* in_sizes, int n_in,
                              void* d_out, int out_size, void* d_ws, size_t ws_size,
                              hipStream_t stream) {
  const float* h   = (const float*)d_in[0];
  const float* rc  = (const float*)d_in[1];
  const float* rs  = (const float*)d_in[2];
  const float* Wq  = (const float*)d_in[3];
  const float* Wk  = (const float*)d_in[4];
  const float* Wv  = (const float*)d_in[5];
  const float* Wo  = (const float*)d_in[6];
  const float* qnw = (const float*)d_in[7];
  const float* knw = (const float*)d_in[8];

  unsigned short* ws    = (unsigned short*)d_ws;
  unsigned short* WTall = ws;                       // 1536*512 (q,k,v contiguous)
  unsigned short* WTo   = WTall + 1536 * 512;       // 512*512
  unsigned short* Hb    = WTo + 512 * 512;          // 4096*512 bf16
  unsigned short* Qw    = Hb + 2097152;
  unsigned short* Kw    = Qw + 2097152;
  unsigned short* Vw    = Kw + 2097152;
  unsigned short* AOw   = Vw + 2097152;

  cvt_f32_bf16<<<1024, 256, 0, stream>>>(h, Hb);
  transpose_all<<<dim3(8, 8, 4), dim3(64, 4), 0, stream>>>(Wq, Wk, Wv, Wo, WTall);

  qkv_fused<<<dim3(32, 12), 256, 0, stream>>>(Hb, WTall, qnw, knw, rc, rs,
                                              Qw, Kw, Vw);

  attn_mfma<<<dim3(32, 16), 256, 0, stream>>>(Qw, Kw, Vw, AOw);

  out_gemm128<<<dim3(32, 4), 256, 0, stream>>>(AOw, WTo, (float*)d_out);
}

// Round 5
// 114.127 us; speedup vs baseline: 1.8960x; 1.0244x over previous
//
#include <hip/hip_runtime.h>
#include <hip/hip_bf16.h>
#include <cmath>

#define Bb 2
#define Tt 2048
#define Dd 512
#define Hh 8
#define Cc 64
#define WINw 128

using u16x8 = __attribute__((ext_vector_type(8))) unsigned short;
using s16x8 = __attribute__((ext_vector_type(8))) short;
using f32x4 = __attribute__((ext_vector_type(4))) float;

__device__ __forceinline__ float bf2f(unsigned short u) {
  union { unsigned int i; float f; } v; v.i = ((unsigned int)u) << 16; return v.f;
}
__device__ __forceinline__ unsigned short f2bf(float f) {
  __hip_bfloat16 b = __float2bfloat16(f);
  return *reinterpret_cast<unsigned short*>(&b);
}

// async global->LDS, 16B/lane; dest = uniform base + lane*16 (m97/m104)
#define GLD16(gp, lp)                                                        \
  __builtin_amdgcn_global_load_lds(                                          \
      (const __attribute__((address_space(1))) unsigned int*)(gp),           \
      (__attribute__((address_space(3))) unsigned int*)(lp), 16, 0, 0)

// ---- prep: z<4 -> transpose+cvt weight z into WTall; z==4 -> cvt h ---------
__global__ __launch_bounds__(256) void prep_all(
    const float* __restrict__ s0, const float* __restrict__ s1,
    const float* __restrict__ s2, const float* __restrict__ s3,
    unsigned short* __restrict__ d,        // 4 transposed mats, 512*512 each
    const float* __restrict__ hsrc, unsigned short* __restrict__ hdst) {
  int tid = threadIdx.x;
  if (blockIdx.z == 4) {
    int gid = ((int)blockIdx.y * 8 + blockIdx.x) * 256 + tid;  // 0..16383
    #pragma unroll
    for (int s = 0; s < 16; ++s) {
      size_t i = ((size_t)s * 16384 + gid) * 8;
      const float4* g = (const float4*)&hsrc[i];
      float4 f0 = g[0], f1 = g[1];
      u16x8 o = {f2bf(f0.x), f2bf(f0.y), f2bf(f0.z), f2bf(f0.w),
                 f2bf(f1.x), f2bf(f1.y), f2bf(f1.z), f2bf(f1.w)};
      *(u16x8*)&hdst[i] = o;
    }
    return;
  }
  __shared__ unsigned short tile[64 * 65];
  const float* srcs[4] = {s0, s1, s2, s3};
  const float* src = srcs[blockIdx.z];
  unsigned short* dst = d + (size_t)blockIdx.z * 512 * 512;
  int n0 = blockIdx.x * 64, k0 = blockIdx.y * 64;
  int tx = tid & 63, ty = tid >> 6;
  #pragma unroll
  for (int i = 0; i < 16; ++i) {
    int k = ty * 16 + i;
    tile[k * 65 + tx] = f2bf(src[(k0 + k) * 512 + n0 + tx]);
  }
  __syncthreads();
  #pragma unroll
  for (int i = 0; i < 16; ++i) {
    int n = ty * 16 + i;
    dst[(n0 + n) * 512 + k0 + tx] = tile[tx * 65 + n];
  }
}

// ---------------- fused QKV GEMM (m97-style) + RMSNorm + RoPE ---------------
// 128x128 tile, BK=64. LDS tiles unpadded [row][64], column-block swizzle:
// LDS[row][cbp] holds global block cb = cbp ^ (row&7) (16B blocks).
__global__ __launch_bounds__(256) void qkv_fused(
    const unsigned short* __restrict__ Hb,     // (4096,512) bf16
    const unsigned short* __restrict__ WTall,  // (1536,512) bf16 [n][k]
    const float* __restrict__ qnw, const float* __restrict__ knw,
    const float* __restrict__ rcos, const float* __restrict__ rsin,
    unsigned short* __restrict__ Qw, unsigned short* __restrict__ Kw,
    unsigned short* __restrict__ Vw) {
  __shared__ alignas(16) unsigned short Al[128 * 64];
  __shared__ alignas(16) unsigned short Bl[128 * 64];
  int tid = threadIdx.x;
  int wave = tid >> 6, lane = tid & 63;
  int ln = lane & 15, qd = lane >> 4;
  int wm = wave >> 1, wn = wave & 1;
  int m0 = blockIdx.x * 128, n0 = blockIdx.y * 128;

  f32x4 acc[4][4];
  #pragma unroll
  for (int mi = 0; mi < 4; ++mi)
    #pragma unroll
    for (int ni = 0; ni < 4; ++ni) acc[mi][ni] = f32x4{0.f, 0.f, 0.f, 0.f};

  for (int k0 = 0; k0 < 512; k0 += 64) {
    #pragma unroll
    for (int s = 0; s < 4; ++s) {
      int q = s * 4 + wave;              // chunk 0..15 (1024B each)
      int L = q * 64 + lane;             // 16B-unit linear index
      int row = L >> 3;
      int cb = (L & 7) ^ (row & 7);      // swizzled source block
      const unsigned short* ga = &Hb[(size_t)(m0 + row) * 512 + k0 + cb * 8];
      GLD16(ga, (char*)Al + q * 1024);
      const unsigned short* gb = &WTall[(size_t)(n0 + row) * 512 + k0 + cb * 8];
      GLD16(gb, (char*)Bl + q * 1024);
    }
    __syncthreads();
    #pragma unroll
    for (int half = 0; half < 2; ++half) {
      s16x8 af[4], bfr[4];
      #pragma unroll
      for (int mi = 0; mi < 4; ++mi) {
        int ar = wm * 64 + mi * 16 + ln;
        int cbp = (qd + half * 4) ^ (ar & 7);
        af[mi] = *(const s16x8*)((const char*)Al + ar * 128 + cbp * 16);
      }
      #pragma unroll
      for (int ni = 0; ni < 4; ++ni) {
        int br = wn * 64 + ni * 16 + ln;
        int cbp = (qd + half * 4) ^ (br & 7);
        bfr[ni] = *(const s16x8*)((const char*)Bl + br * 128 + cbp * 16);
      }
      #pragma unroll
      for (int mi = 0; mi < 4; ++mi)
        #pragma unroll
        for (int ni = 0; ni < 4; ++ni)
          acc[mi][ni] = __builtin_amdgcn_mfma_f32_16x16x32_bf16(
              af[mi], bfr[ni], acc[mi][ni], 0, 0, 0);
    }
    __syncthreads();
  }

  // epilogue: wave-uniform head
  int gh = blockIdx.y * 2 + wn;          // 0..23
  int mat = gh >> 3, head = gh & 7;
  unsigned short* Out = (mat == 0) ? Qw : (mat == 1) ? Kw : Vw;
  const float* nw = (mat == 0) ? qnw : knw;
  bool do_rope = (mat < 2);

  #pragma unroll
  for (int mi = 0; mi < 4; ++mi) {
    float vals[4][4];  // [ni][r]
    #pragma unroll
    for (int ni = 0; ni < 4; ++ni)
      #pragma unroll
      for (int r = 0; r < 4; ++r) vals[ni][r] = acc[mi][ni][r];

    if (do_rope) {
      #pragma unroll
      for (int r = 0; r < 4; ++r) {
        float ss = 0.f;
        #pragma unroll
        for (int ni = 0; ni < 4; ++ni) ss += vals[ni][r] * vals[ni][r];
        ss += __shfl_xor(ss, 1, 64);
        ss += __shfl_xor(ss, 2, 64);
        ss += __shfl_xor(ss, 4, 64);
        ss += __shfl_xor(ss, 8, 64);
        float nrm = rsqrtf(ss * (1.0f / 64.0f) + 1e-6f);
        #pragma unroll
        for (int ni = 0; ni < 4; ++ni) vals[ni][r] *= nrm;
      }
      #pragma unroll
      for (int ni = 0; ni < 4; ++ni) {
        float w = nw[ni * 16 + ln];
        #pragma unroll
        for (int r = 0; r < 4; ++r) vals[ni][r] *= w;
      }
      float res[4][4];
      #pragma unroll
      for (int r = 0; r < 4; ++r) {
        int row = m0 + wm * 64 + mi * 16 + qd * 4 + r;
        int t = row & (Tt - 1);
        #pragma unroll
        for (int ni = 0; ni < 4; ++ni) {
          int c = ni * 16 + ln;
          float cs = rcos[t * 64 + c];
          float sn = rsin[t * 64 + c];
          float part = vals[ni ^ 2][r];
          float rot = (ni < 2) ? -part : part;
          res[ni][r] = vals[ni][r] * cs + rot * sn;
        }
      }
      #pragma unroll
      for (int ni = 0; ni < 4; ++ni)
        #pragma unroll
        for (int r = 0; r < 4; ++r) vals[ni][r] = res[ni][r];
    }

    #pragma unroll
    for (int r = 0; r < 4; ++r) {
      int row = m0 + wm * 64 + mi * 16 + qd * 4 + r;
      int b = row >> 11, t = row & (Tt - 1);
      unsigned short* op = &Out[(((size_t)b * Hh + head) * Tt + t) * 64 + ln];
      #pragma unroll
      for (int ni = 0; ni < 4; ++ni) op[ni * 16] = f2bf(vals[ni][r]);
    }
  }
}

// ---------- MFMA sliding-window attention: 64 queries / block ---------------
__global__ __launch_bounds__(256) void attn_mfma(
    const unsigned short* __restrict__ Q,  // (B,H,T,C) bf16
    const unsigned short* __restrict__ K,
    const unsigned short* __restrict__ V,
    unsigned short* __restrict__ AO) {     // (B,T,H,C) bf16
  __shared__ alignas(16) unsigned short Ql[64 * 72];
  __shared__ alignas(16) unsigned short KP[192 * 72];  // K tile; then P[64][200]
  __shared__ alignas(16) unsigned short Vt[64 * 200];  // V^T: [c][kk]

  int tid = threadIdx.x;
  int wave = tid >> 6, lane = tid & 63;
  int ln = lane & 15, qd = lane >> 4;
  int qtile = blockIdx.x, bh = blockIdx.y;
  int t0 = qtile * 64;
  int kb = t0 - 128;

  const unsigned short* Qg = Q + ((size_t)bh * Tt + t0) * 64;
  const unsigned short* Kg = K + (size_t)bh * Tt * 64;
  const unsigned short* Vg = V + (size_t)bh * Tt * 64;

  int srow = tid >> 2;
  int scol = (tid & 3) * 16;

  {
    const u16x8* g = (const u16x8*)&Qg[srow * 64 + scol];
    u16x8 a0 = g[0], a1 = g[1];
    *(u16x8*)&Ql[srow * 72 + scol] = a0;
    *(u16x8*)&Ql[srow * 72 + scol + 8] = a1;
  }
  #pragma unroll
  for (int p = 0; p < 3; ++p) {
    int row = p * 64 + srow;            // 0..191
    int kg = kb + row; if (kg < 0) kg = 0;
    const u16x8* gk = (const u16x8*)&Kg[kg * 64 + scol];
    u16x8 k0 = gk[0], k1 = gk[1];
    const u16x8* gv = (const u16x8*)&Vg[kg * 64 + scol];
    u16x8 v0 = gv[0], v1 = gv[1];
    *(u16x8*)&KP[row * 72 + scol] = k0;
    *(u16x8*)&KP[row * 72 + scol + 8] = k1;
    #pragma unroll
    for (int j = 0; j < 8; ++j) {
      Vt[(scol + j) * 200 + row] = v0[j];
      Vt[(scol + 8 + j) * 200 + row] = v1[j];
    }
  }
  __syncthreads();

  int q0 = wave * 16;
  s16x8 aq0 = *(const s16x8*)&Ql[(q0 + ln) * 72 + qd * 8];
  s16x8 aq1 = *(const s16x8*)&Ql[(q0 + ln) * 72 + 32 + qd * 8];
  f32x4 sf[12];
  #pragma unroll
  for (int nt = 0; nt < 12; ++nt) {
    s16x8 b0 = *(const s16x8*)&KP[(nt * 16 + ln) * 72 + qd * 8];
    s16x8 b1 = *(const s16x8*)&KP[(nt * 16 + ln) * 72 + 32 + qd * 8];
    f32x4 acc = {0.f, 0.f, 0.f, 0.f};
    acc = __builtin_amdgcn_mfma_f32_16x16x32_bf16(aq0, b0, acc, 0, 0, 0);
    acc = __builtin_amdgcn_mfma_f32_16x16x32_bf16(aq1, b1, acc, 0, 0, 0);
    sf[nt] = acc;
  }
  __syncthreads();

  unsigned short* Pl = KP;
  int ok0 = (t0 < 128) ? (128 - t0) : 0;
  #pragma unroll
  for (int r = 0; r < 4; ++r) {
    int lq = q0 + qd * 4 + r;
    float mx = -INFINITY;
    #pragma unroll
    for (int nt = 0; nt < 12; ++nt) {
      int kk = nt * 16 + ln;
      bool valid = (kk > lq) && (kk <= lq + 128) && (kk >= ok0);
      float s = valid ? sf[nt][r] * 0.125f : -INFINITY;
      sf[nt][r] = s;
      mx = fmaxf(mx, s);
    }
    mx = fmaxf(mx, __shfl_xor(mx, 1, 64));
    mx = fmaxf(mx, __shfl_xor(mx, 2, 64));
    mx = fmaxf(mx, __shfl_xor(mx, 4, 64));
    mx = fmaxf(mx, __shfl_xor(mx, 8, 64));
    float sum = 0.f;
    #pragma unroll
    for (int nt = 0; nt < 12; ++nt) {
      float e = __expf(sf[nt][r] - mx);
      sf[nt][r] = e;
      sum += e;
    }
    sum += __shfl_xor(sum, 1, 64);
    sum += __shfl_xor(sum, 2, 64);
    sum += __shfl_xor(sum, 4, 64);
    sum += __shfl_xor(sum, 8, 64);
    float inv = 1.0f / sum;
    #pragma unroll
    for (int nt = 0; nt < 12; ++nt)
      Pl[lq * 200 + nt * 16 + ln] = f2bf(sf[nt][r] * inv);
  }
  __syncthreads();

  f32x4 oa[4] = {f32x4{0,0,0,0}, f32x4{0,0,0,0}, f32x4{0,0,0,0}, f32x4{0,0,0,0}};
  #pragma unroll
  for (int s = 0; s < 6; ++s) {
    s16x8 ap = *(const s16x8*)&Pl[(q0 + ln) * 200 + s * 32 + qd * 8];
    #pragma unroll
    for (int nt = 0; nt < 4; ++nt) {
      s16x8 bv = *(const s16x8*)&Vt[(nt * 16 + ln) * 200 + s * 32 + qd * 8];
      oa[nt] = __builtin_amdgcn_mfma_f32_16x16x32_bf16(ap, bv, oa[nt], 0, 0, 0);
    }
  }

  int b = bh >> 3, h = bh & 7;
  #pragma unroll
  for (int r = 0; r < 4; ++r) {
    int t = t0 + q0 + qd * 4 + r;
    unsigned short* op = &AO[(((size_t)b * Tt + t) * Hh + h) * 64 + ln];
    #pragma unroll
    for (int nt = 0; nt < 4; ++nt) op[nt * 16] = f2bf(oa[nt][r]);
  }
}

// ------------- output GEMM (64x128 tile, m97-style): AO @ W_o -> f32 --------
__global__ __launch_bounds__(256) void out_gemm(
    const unsigned short* __restrict__ Am,  // (4096,512) bf16
    const unsigned short* __restrict__ WT,  // (512,512) bf16 [n][k]
    float* __restrict__ Out) {              // (4096,512) f32
  __shared__ alignas(16) unsigned short Al[64 * 64];    // 8KB, 8 chunks
  __shared__ alignas(16) unsigned short Bl[128 * 64];   // 16KB, 16 chunks
  int tid = threadIdx.x;
  int wave = tid >> 6, lane = tid & 63;
  int ln = lane & 15, qd = lane >> 4;
  int wm = wave >> 1, wn = wave & 1;
  int m0 = blockIdx.x * 64, n0 = blockIdx.y * 128;

  f32x4 acc[2][4];
  #pragma unroll
  for (int mi = 0; mi < 2; ++mi)
    #pragma unroll
    for (int ni = 0; ni < 4; ++ni) acc[mi][ni] = f32x4{0.f, 0.f, 0.f, 0.f};

  for (int k0 = 0; k0 < 512; k0 += 64) {
    #pragma unroll
    for (int s = 0; s < 2; ++s) {       // A: 8 chunks, 2 per wave
      int q = s * 4 + wave;
      int L = q * 64 + lane;
      int row = L >> 3;
      int cb = (L & 7) ^ (row & 7);
      const unsigned short* ga = &Am[(size_t)(m0 + row) * 512 + k0 + cb * 8];
      GLD16(ga, (char*)Al + q * 1024);
    }
    #pragma unroll
    for (int s = 0; s < 4; ++s) {       // B: 16 chunks, 4 per wave
      int q = s * 4 + wave;
      int L = q * 64 + lane;
      int row = L >> 3;
      int cb = (L & 7) ^ (row & 7);
      const unsigned short* gb = &WT[(size_t)(n0 + row) * 512 + k0 + cb * 8];
      GLD16(gb, (char*)Bl + q * 1024);
    }
    __syncthreads();
    #pragma unroll
    for (int half = 0; half < 2; ++half) {
      s16x8 af[2], bfr[4];
      #pragma unroll
      for (int mi = 0; mi < 2; ++mi) {
        int ar = wm * 32 + mi * 16 + ln;
        int cbp = (qd + half * 4) ^ (ar & 7);
        af[mi] = *(const s16x8*)((const char*)Al + ar * 128 + cbp * 16);
      }
      #pragma unroll
      for (int ni = 0; ni < 4; ++ni) {
        int br = wn * 64 + ni * 16 + ln;
        int cbp = (qd + half * 4) ^ (br & 7);
        bfr[ni] = *(const s16x8*)((const char*)Bl + br * 128 + cbp * 16);
      }
      #pragma unroll
      for (int mi = 0; mi < 2; ++mi)
        #pragma unroll
        for (int ni = 0; ni < 4; ++ni)
          acc[mi][ni] = __builtin_amdgcn_mfma_f32_16x16x32_bf16(
              af[mi], bfr[ni], acc[mi][ni], 0, 0, 0);
    }
    __syncthreads();
  }

  #pragma unroll
  for (int mi = 0; mi < 2; ++mi)
    #pragma unroll
    for (int r = 0; r < 4; ++r) {
      int row = m0 + wm * 32 + mi * 16 + qd * 4 + r;
      #pragma unroll
      for (int ni = 0; ni < 4; ++ni)
        Out[(size_t)row * 512 + n0 + wn * 64 + ni * 16 + ln] = acc[mi][ni][r];
    }
}

extern "C" void kernel_launch(void* const* d_in, const int* in_sizes, int n_in,
                              void* d_out, int out_size, void* d_ws, size_t ws_size,
                              hipStream_t stream) {
  const float* h   = (const float*)d_in[0];
  const float* rc  = (const float*)d_in[1];
  const float* rs  = (const float*)d_in[2];
  const float* Wq  = (const float*)d_in[3];
  const float* Wk  = (const float*)d_in[4];
  const float* Wv  = (const float*)d_in[5];
  const float* Wo  = (const float*)d_in[6];
  const float* qnw = (const float*)d_in[7];
  const float* knw = (const float*)d_in[8];

  unsigned short* ws    = (unsigned short*)d_ws;
  unsigned short* WTall = ws;                       // 1536*512 (q,k,v contiguous)
  unsigned short* WTo   = WTall + 1536 * 512;       // 512*512
  unsigned short* Hb    = WTo + 512 * 512;          // 4096*512 bf16
  unsigned short* Qw    = Hb + 2097152;
  unsigned short* Kw    = Qw + 2097152;
  unsigned short* Vw    = Kw + 2097152;
  unsigned short* AOw   = Vw + 2097152;

  prep_all<<<dim3(8, 8, 5), 256, 0, stream>>>(Wq, Wk, Wv, Wo, WTall, h, Hb);

  qkv_fused<<<dim3(32, 12), 256, 0, stream>>>(Hb, WTall, qnw, knw, rc, rs,
                                              Qw, Kw, Vw);

  attn_mfma<<<dim3(32, 16), 256, 0, stream>>>(Qw, Kw, Vw, AOw);

  out_gemm<<<dim3(64, 4), 256, 0, stream>>>(AOw, WTo, (float*)d_out);
}

// Round 6
// 113.729 us; speedup vs baseline: 1.9026x; 1.0035x over previous
//
#include <hip/hip_runtime.h>
#include <hip/hip_bf16.h>
#include <cmath>

#define Bb 2
#define Tt 2048
#define Dd 512
#define Hh 8
#define Cc 64
#define WINw 128

using u16x8 = __attribute__((ext_vector_type(8))) unsigned short;
using s16x8 = __attribute__((ext_vector_type(8))) short;
using f32x4 = __attribute__((ext_vector_type(4))) float;

__device__ __forceinline__ float bf2f(unsigned short u) {
  union { unsigned int i; float f; } v; v.i = ((unsigned int)u) << 16; return v.f;
}
__device__ __forceinline__ unsigned short f2bf(float f) {
  __hip_bfloat16 b = __float2bfloat16(f);
  return *reinterpret_cast<unsigned short*>(&b);
}

// async global->LDS, 16B/lane; dest = uniform base + lane*16 (m97/m104)
#define GLD16(gp, lp)                                                        \
  __builtin_amdgcn_global_load_lds(                                          \
      (const __attribute__((address_space(1))) unsigned int*)(gp),           \
      (__attribute__((address_space(3))) unsigned int*)(lp), 16, 0, 0)

// ---- prep: z<4 -> transpose+cvt weight z into WTall; z==4 -> cvt h ---------
__global__ __launch_bounds__(256) void prep_all(
    const float* __restrict__ s0, const float* __restrict__ s1,
    const float* __restrict__ s2, const float* __restrict__ s3,
    unsigned short* __restrict__ d,
    const float* __restrict__ hsrc, unsigned short* __restrict__ hdst) {
  int tid = threadIdx.x;
  if (blockIdx.z == 4) {
    int gid = ((int)blockIdx.y * 8 + blockIdx.x) * 256 + tid;  // 0..16383
    #pragma unroll
    for (int s = 0; s < 16; ++s) {
      size_t i = ((size_t)s * 16384 + gid) * 8;
      const float4* g = (const float4*)&hsrc[i];
      float4 f0 = g[0], f1 = g[1];
      u16x8 o = {f2bf(f0.x), f2bf(f0.y), f2bf(f0.z), f2bf(f0.w),
                 f2bf(f1.x), f2bf(f1.y), f2bf(f1.z), f2bf(f1.w)};
      *(u16x8*)&hdst[i] = o;
    }
    return;
  }
  __shared__ unsigned short tile[64 * 65];
  const float* srcs[4] = {s0, s1, s2, s3};
  const float* src = srcs[blockIdx.z];
  unsigned short* dst = d + (size_t)blockIdx.z * 512 * 512;
  int n0 = blockIdx.x * 64, k0 = blockIdx.y * 64;
  int tx = tid & 63, ty = tid >> 6;
  #pragma unroll
  for (int i = 0; i < 16; ++i) {
    int k = ty * 16 + i;
    tile[k * 65 + tx] = f2bf(src[(k0 + k) * 512 + n0 + tx]);
  }
  __syncthreads();
  #pragma unroll
  for (int i = 0; i < 16; ++i) {
    int n = ty * 16 + i;
    dst[(n0 + n) * 512 + k0 + tx] = tile[tx * 65 + n];
  }
}

// -------- fused QKV GEMM + RMSNorm + RoPE, coalesced LDS-transpose epilogue -
// Q,K out: (B,H,T,C). V out: (B,H,C,T) (transposed for attention staging).
__global__ __launch_bounds__(256) void qkv_fused(
    const unsigned short* __restrict__ Hb,     // (4096,512) bf16
    const unsigned short* __restrict__ WTall,  // (1536,512) bf16 [n][k]
    const float* __restrict__ qnw, const float* __restrict__ knw,
    const float* __restrict__ rcos, const float* __restrict__ rsin,
    unsigned short* __restrict__ Qw, unsigned short* __restrict__ Kw,
    unsigned short* __restrict__ Vw) {
  __shared__ alignas(16) unsigned short S[18432];   // 36 KB union
  unsigned short* Al = S;            // [128*64] GEMM A
  unsigned short* Bl = S + 8192;     // [128*64] GEMM B
  int tid = threadIdx.x;
  int wave = tid >> 6, lane = tid & 63;
  int ln = lane & 15, qd = lane >> 4;
  int wm = wave >> 1, wn = wave & 1;
  int m0 = blockIdx.x * 128, n0 = blockIdx.y * 128;

  f32x4 acc[4][4];
  #pragma unroll
  for (int mi = 0; mi < 4; ++mi)
    #pragma unroll
    for (int ni = 0; ni < 4; ++ni) acc[mi][ni] = f32x4{0.f, 0.f, 0.f, 0.f};

  for (int k0 = 0; k0 < 512; k0 += 64) {
    #pragma unroll
    for (int s = 0; s < 4; ++s) {
      int q = s * 4 + wave;
      int L = q * 64 + lane;
      int row = L >> 3;
      int cb = (L & 7) ^ (row & 7);
      GLD16(&Hb[(size_t)(m0 + row) * 512 + k0 + cb * 8], (char*)Al + q * 1024);
      GLD16(&WTall[(size_t)(n0 + row) * 512 + k0 + cb * 8], (char*)Bl + q * 1024);
    }
    __syncthreads();
    #pragma unroll
    for (int half = 0; half < 2; ++half) {
      s16x8 af[4], bfr[4];
      #pragma unroll
      for (int mi = 0; mi < 4; ++mi) {
        int ar = wm * 64 + mi * 16 + ln;
        int cbp = (qd + half * 4) ^ (ar & 7);
        af[mi] = *(const s16x8*)((const char*)Al + ar * 128 + cbp * 16);
      }
      #pragma unroll
      for (int ni = 0; ni < 4; ++ni) {
        int br = wn * 64 + ni * 16 + ln;
        int cbp = (qd + half * 4) ^ (br & 7);
        bfr[ni] = *(const s16x8*)((const char*)Bl + br * 128 + cbp * 16);
      }
      #pragma unroll
      for (int mi = 0; mi < 4; ++mi)
        #pragma unroll
        for (int ni = 0; ni < 4; ++ni)
          acc[mi][ni] = __builtin_amdgcn_mfma_f32_16x16x32_bf16(
              af[mi], bfr[ni], acc[mi][ni], 0, 0, 0);
    }
    __syncthreads();   // also makes S safe for epilogue reuse after last iter
  }

  // ---- epilogue: norm/rope in regs, per-wave LDS transpose, u16x8 stores ----
  unsigned short* Wl = S + wave * 4608;        // 64 rows x 72, wave-private
  int gh = blockIdx.y * 2 + wn;                // 0..23
  int mat = gh >> 3, head = gh & 7;
  const float* nw = (mat == 0) ? qnw : knw;
  bool do_rope = (mat < 2);
  int mrow0 = m0 + wm * 64;
  int b = mrow0 >> 11, tb = mrow0 & (Tt - 1);

  #pragma unroll
  for (int mi = 0; mi < 4; ++mi) {
    float vals[4][4];
    #pragma unroll
    for (int ni = 0; ni < 4; ++ni)
      #pragma unroll
      for (int r = 0; r < 4; ++r) vals[ni][r] = acc[mi][ni][r];

    if (do_rope) {
      #pragma unroll
      for (int r = 0; r < 4; ++r) {
        float ss = 0.f;
        #pragma unroll
        for (int ni = 0; ni < 4; ++ni) ss += vals[ni][r] * vals[ni][r];
        ss += __shfl_xor(ss, 1, 64);
        ss += __shfl_xor(ss, 2, 64);
        ss += __shfl_xor(ss, 4, 64);
        ss += __shfl_xor(ss, 8, 64);
        float nrm = rsqrtf(ss * (1.0f / 64.0f) + 1e-6f);
        #pragma unroll
        for (int ni = 0; ni < 4; ++ni) vals[ni][r] *= nrm;
      }
      #pragma unroll
      for (int ni = 0; ni < 4; ++ni) {
        float w = nw[ni * 16 + ln];
        #pragma unroll
        for (int r = 0; r < 4; ++r) vals[ni][r] *= w;
      }
      float res[4][4];
      #pragma unroll
      for (int r = 0; r < 4; ++r) {
        int t = (tb + mi * 16 + qd * 4 + r);
        #pragma unroll
        for (int ni = 0; ni < 4; ++ni) {
          int c = ni * 16 + ln;
          float cs = rcos[t * 64 + c];
          float sn = rsin[t * 64 + c];
          float part = vals[ni ^ 2][r];
          float rot = (ni < 2) ? -part : part;
          res[ni][r] = vals[ni][r] * cs + rot * sn;
        }
      }
      #pragma unroll
      for (int ni = 0; ni < 4; ++ni)
        #pragma unroll
        for (int r = 0; r < 4; ++r) vals[ni][r] = res[ni][r];
    }

    if (mat < 2) {   // layout [t_local][c]
      #pragma unroll
      for (int ni = 0; ni < 4; ++ni)
        #pragma unroll
        for (int r = 0; r < 4; ++r)
          Wl[(mi * 16 + qd * 4 + r) * 72 + ni * 16 + ln] = f2bf(vals[ni][r]);
    } else {         // V: layout [c][t_local]
      #pragma unroll
      for (int ni = 0; ni < 4; ++ni)
        #pragma unroll
        for (int r = 0; r < 4; ++r)
          Wl[(ni * 16 + ln) * 72 + mi * 16 + qd * 4 + r] = f2bf(vals[ni][r]);
    }
  }

  if (mat < 2) {
    unsigned short* Og =
        ((mat == 0) ? Qw : Kw) + (((size_t)b * Hh + head) * Tt + tb) * 64;
    #pragma unroll
    for (int i = 0; i < 8; ++i) {
      int idx = i * 64 + lane;
      int rr = idx >> 3, cc = (idx & 7) * 8;
      *(u16x8*)&Og[rr * 64 + cc] = *(const u16x8*)&Wl[rr * 72 + cc];
    }
  } else {
    unsigned short* Og = Vw + (((size_t)b * Hh + head) * 64) * 2048 + tb;
    #pragma unroll
    for (int i = 0; i < 8; ++i) {
      int idx = i * 64 + lane;
      int rr = idx >> 3, cc = (idx & 7) * 8;
      *(u16x8*)&Og[(size_t)rr * 2048 + cc] = *(const u16x8*)&Wl[rr * 72 + cc];
    }
  }
}

// ---------- MFMA sliding-window attention: 64 queries / block ---------------
// Q,K: (B,H,T,C); V: (B,H,C,T). AO: (B,T,H,C). 53 KB LDS -> 3 blocks/CU.
__global__ __launch_bounds__(256) void attn_mfma(
    const unsigned short* __restrict__ Q,
    const unsigned short* __restrict__ K,
    const unsigned short* __restrict__ Vg,
    unsigned short* __restrict__ AO) {
  __shared__ alignas(16) unsigned short KP[192 * 72];  // K tile; then P[64][200]
  __shared__ alignas(16) unsigned short Vt[64 * 200];  // [c][kk]
  int tid = threadIdx.x;
  int wave = tid >> 6, lane = tid & 63;
  int ln = lane & 15, qd = lane >> 4;
  int t0 = blockIdx.x * 64, bh = blockIdx.y;
  int kb = t0 - 128;
  int q0 = wave * 16;

  const unsigned short* Kg = K + (size_t)bh * Tt * 64;
  const unsigned short* Vb = Vg + (size_t)bh * 64 * 2048;

  // K stage (rows = keys, C contiguous)
  int srow = tid >> 2, scol = (tid & 3) * 16;
  #pragma unroll
  for (int p = 0; p < 3; ++p) {
    int row = p * 64 + srow;
    int kg = kb + row; if (kg < 0) kg = 0;
    const u16x8* gk = (const u16x8*)&Kg[(size_t)kg * 64 + scol];
    u16x8 k0v = gk[0], k1v = gk[1];
    *(u16x8*)&KP[row * 72 + scol] = k0v;
    *(u16x8*)&KP[row * 72 + scol + 8] = k1v;
  }
  // V stage: coalesced row copies (V already transposed); kb<0 reads land in
  // the preceding K buffer -- finite garbage, masked by P=0.
  #pragma unroll
  for (int j = 0; j < 3; ++j)
    #pragma unroll
    for (int it = 0; it < 2; ++it) {
      int idx = it * 256 + tid;
      int row = idx >> 3, ch = (idx & 7) * 8;
      u16x8 v = *(const u16x8*)&Vb[(size_t)row * 2048 + kb + j * 64 + ch];
      *(u16x8*)&Vt[row * 200 + j * 64 + ch] = v;
    }
  // Q A-frags direct from global (wave-private)
  const unsigned short* Qg = Q + ((size_t)bh * Tt + t0 + q0) * 64;
  s16x8 aq0 = *(const s16x8*)&Qg[ln * 64 + qd * 8];
  s16x8 aq1 = *(const s16x8*)&Qg[ln * 64 + 32 + qd * 8];
  __syncthreads();

  // S = Q K^T
  f32x4 sf[12];
  #pragma unroll
  for (int nt = 0; nt < 12; ++nt) {
    s16x8 b0 = *(const s16x8*)&KP[(nt * 16 + ln) * 72 + qd * 8];
    s16x8 b1 = *(const s16x8*)&KP[(nt * 16 + ln) * 72 + 32 + qd * 8];
    f32x4 a = {0.f, 0.f, 0.f, 0.f};
    a = __builtin_amdgcn_mfma_f32_16x16x32_bf16(aq0, b0, a, 0, 0, 0);
    a = __builtin_amdgcn_mfma_f32_16x16x32_bf16(aq1, b1, a, 0, 0, 0);
    sf[nt] = a;
  }
  __syncthreads();  // all K reads done; safe to overwrite KP with P

  unsigned short* Pl = KP;  // P[64][200], wave w owns rows q0..q0+15
  int ok0 = (t0 < 128) ? (128 - t0) : 0;
  #pragma unroll
  for (int r = 0; r < 4; ++r) {
    int lq = q0 + qd * 4 + r;
    float mx = -INFINITY;
    #pragma unroll
    for (int nt = 0; nt < 12; ++nt) {
      int kk = nt * 16 + ln;
      bool valid = (kk > lq) && (kk <= lq + 128) && (kk >= ok0);
      float s = valid ? sf[nt][r] * 0.125f : -INFINITY;
      sf[nt][r] = s;
      mx = fmaxf(mx, s);
    }
    mx = fmaxf(mx, __shfl_xor(mx, 1, 64));
    mx = fmaxf(mx, __shfl_xor(mx, 2, 64));
    mx = fmaxf(mx, __shfl_xor(mx, 4, 64));
    mx = fmaxf(mx, __shfl_xor(mx, 8, 64));
    float sum = 0.f;
    #pragma unroll
    for (int nt = 0; nt < 12; ++nt) {
      float e = __expf(sf[nt][r] - mx);
      sf[nt][r] = e;
      sum += e;
    }
    sum += __shfl_xor(sum, 1, 64);
    sum += __shfl_xor(sum, 2, 64);
    sum += __shfl_xor(sum, 4, 64);
    sum += __shfl_xor(sum, 8, 64);
    float inv = 1.0f / sum;
    #pragma unroll
    for (int nt = 0; nt < 12; ++nt)
      Pl[lq * 200 + nt * 16 + ln] = f2bf(sf[nt][r] * inv);
  }
  // no barrier: P rows + O-stage region are wave-private, Vt is stable

  f32x4 oa[4] = {f32x4{0,0,0,0}, f32x4{0,0,0,0}, f32x4{0,0,0,0}, f32x4{0,0,0,0}};
  #pragma unroll
  for (int s = 0; s < 6; ++s) {
    s16x8 ap = *(const s16x8*)&Pl[(q0 + ln) * 200 + s * 32 + qd * 8];
    #pragma unroll
    for (int nt = 0; nt < 4; ++nt) {
      s16x8 bv = *(const s16x8*)&Vt[(nt * 16 + ln) * 200 + s * 32 + qd * 8];
      oa[nt] = __builtin_amdgcn_mfma_f32_16x16x32_bf16(ap, bv, oa[nt], 0, 0, 0);
    }
  }

  // coalesced output via own LDS slice
  unsigned short* Ow = KP + q0 * 200;  // 16 rows x 72 within own P region
  #pragma unroll
  for (int ni = 0; ni < 4; ++ni)
    #pragma unroll
    for (int r = 0; r < 4; ++r)
      Ow[(qd * 4 + r) * 72 + ni * 16 + ln] = f2bf(oa[ni][r]);
  int b = bh >> 3, h = bh & 7;
  #pragma unroll
  for (int i = 0; i < 2; ++i) {
    int idx = i * 64 + lane;
    int rr = idx >> 3, cc = (idx & 7) * 8;
    *(u16x8*)&AO[((size_t)(b * Tt + t0 + q0 + rr) * Hh + h) * 64 + cc] =
        *(const u16x8*)&Ow[rr * 72 + cc];
  }
}

// ------------- output GEMM (64x128 tile, m97-style): AO @ W_o -> f32 --------
__global__ __launch_bounds__(256) void out_gemm(
    const unsigned short* __restrict__ Am,  // (4096,512) bf16
    const unsigned short* __restrict__ WT,  // (512,512) bf16 [n][k]
    float* __restrict__ Out) {              // (4096,512) f32
  __shared__ alignas(16) unsigned short Al[64 * 64];
  __shared__ alignas(16) unsigned short Bl[128 * 64];
  int tid = threadIdx.x;
  int wave = tid >> 6, lane = tid & 63;
  int ln = lane & 15, qd = lane >> 4;
  int wm = wave >> 1, wn = wave & 1;
  int m0 = blockIdx.x * 64, n0 = blockIdx.y * 128;

  f32x4 acc[2][4];
  #pragma unroll
  for (int mi = 0; mi < 2; ++mi)
    #pragma unroll
    for (int ni = 0; ni < 4; ++ni) acc[mi][ni] = f32x4{0.f, 0.f, 0.f, 0.f};

  for (int k0 = 0; k0 < 512; k0 += 64) {
    #pragma unroll
    for (int s = 0; s < 2; ++s) {
      int q = s * 4 + wave;
      int L = q * 64 + lane;
      int row = L >> 3;
      int cb = (L & 7) ^ (row & 7);
      GLD16(&Am[(size_t)(m0 + row) * 512 + k0 + cb * 8], (char*)Al + q * 1024);
    }
    #pragma unroll
    for (int s = 0; s < 4; ++s) {
      int q = s * 4 + wave;
      int L = q * 64 + lane;
      int row = L >> 3;
      int cb = (L & 7) ^ (row & 7);
      GLD16(&WT[(size_t)(n0 + row) * 512 + k0 + cb * 8], (char*)Bl + q * 1024);
    }
    __syncthreads();
    #pragma unroll
    for (int half = 0; half < 2; ++half) {
      s16x8 af[2], bfr[4];
      #pragma unroll
      for (int mi = 0; mi < 2; ++mi) {
        int ar = wm * 32 + mi * 16 + ln;
        int cbp = (qd + half * 4) ^ (ar & 7);
        af[mi] = *(const s16x8*)((const char*)Al + ar * 128 + cbp * 16);
      }
      #pragma unroll
      for (int ni = 0; ni < 4; ++ni) {
        int br = wn * 64 + ni * 16 + ln;
        int cbp = (qd + half * 4) ^ (br & 7);
        bfr[ni] = *(const s16x8*)((const char*)Bl + br * 128 + cbp * 16);
      }
      #pragma unroll
      for (int mi = 0; mi < 2; ++mi)
        #pragma unroll
        for (int ni = 0; ni < 4; ++ni)
          acc[mi][ni] = __builtin_amdgcn_mfma_f32_16x16x32_bf16(
              af[mi], bfr[ni], acc[mi][ni], 0, 0, 0);
    }
    __syncthreads();
  }

  #pragma unroll
  for (int mi = 0; mi < 2; ++mi)
    #pragma unroll
    for (int r = 0; r < 4; ++r) {
      int row = m0 + wm * 32 + mi * 16 + qd * 4 + r;
      #pragma unroll
      for (int ni = 0; ni < 4; ++ni)
        Out[(size_t)row * 512 + n0 + wn * 64 + ni * 16 + ln] = acc[mi][ni][r];
    }
}

extern "C" void kernel_launch(void* const* d_in, const int* in_sizes, int n_in,
                              void* d_out, int out_size, void* d_ws, size_t ws_size,
                              hipStream_t stream) {
  const float* h   = (const float*)d_in[0];
  const float* rc  = (const float*)d_in[1];
  const float* rs  = (const float*)d_in[2];
  const float* Wq  = (const float*)d_in[3];
  const float* Wk  = (const float*)d_in[4];
  const float* Wv  = (const float*)d_in[5];
  const float* Wo  = (const float*)d_in[6];
  const float* qnw = (const float*)d_in[7];
  const float* knw = (const float*)d_in[8];

  unsigned short* ws    = (unsigned short*)d_ws;
  unsigned short* WTall = ws;                       // 1536*512 (q,k,v contiguous)
  unsigned short* WTo   = WTall + 1536 * 512;       // 512*512
  unsigned short* Hb    = WTo + 512 * 512;          // 4096*512 bf16
  unsigned short* Qw    = Hb + 2097152;             // (B,H,T,C)
  unsigned short* Kw    = Qw + 2097152;             // (B,H,T,C)
  unsigned short* Vw    = Kw + 2097152;             // (B,H,C,T)
  unsigned short* AOw   = Vw + 2097152;             // (B,T,H,C)

  prep_all<<<dim3(8, 8, 5), 256, 0, stream>>>(Wq, Wk, Wv, Wo, WTall, h, Hb);

  qkv_fused<<<dim3(32, 12), 256, 0, stream>>>(Hb, WTall, qnw, knw, rc, rs,
                                              Qw, Kw, Vw);

  attn_mfma<<<dim3(32, 16), 256, 0, stream>>>(Qw, Kw, Vw, AOw);

  out_gemm<<<dim3(64, 4), 256, 0, stream>>>(AOw, WTo, (float*)d_out);
}

// Round 7
// 106.334 us; speedup vs baseline: 2.0349x; 1.0695x over previous
//
#include <hip/hip_runtime.h>
#include <hip/hip_bf16.h>
#include <cmath>

#define Bb 2
#define Tt 2048
#define Dd 512
#define Hh 8
#define Cc 64
#define WINw 128

using u16x8 = __attribute__((ext_vector_type(8))) unsigned short;
using s16x8 = __attribute__((ext_vector_type(8))) short;
using f32x4 = __attribute__((ext_vector_type(4))) float;

__device__ __forceinline__ float bf2f(unsigned short u) {
  union { unsigned int i; float f; } v; v.i = ((unsigned int)u) << 16; return v.f;
}
__device__ __forceinline__ unsigned short f2bf(float f) {
  __hip_bfloat16 b = __float2bfloat16(f);
  return *reinterpret_cast<unsigned short*>(&b);
}

// async global->LDS, 16B/lane; dest = uniform base + lane*16 (m97/m104)
#define GLD16(gp, lp)                                                        \
  __builtin_amdgcn_global_load_lds(                                          \
      (const __attribute__((address_space(1))) unsigned int*)(gp),           \
      (__attribute__((address_space(3))) unsigned int*)(lp), 16, 0, 0)

// ---- prep: z<4 -> transpose+cvt weight z into WTall; z==4 -> cvt h ---------
__global__ __launch_bounds__(256) void prep_all(
    const float* __restrict__ s0, const float* __restrict__ s1,
    const float* __restrict__ s2, const float* __restrict__ s3,
    unsigned short* __restrict__ d,
    const float* __restrict__ hsrc, unsigned short* __restrict__ hdst) {
  int tid = threadIdx.x;
  if (blockIdx.z == 4) {
    int gid = ((int)blockIdx.y * 8 + blockIdx.x) * 256 + tid;  // 0..16383
    #pragma unroll
    for (int s = 0; s < 16; ++s) {
      size_t i = ((size_t)s * 16384 + gid) * 8;
      const float4* g = (const float4*)&hsrc[i];
      float4 f0 = g[0], f1 = g[1];
      u16x8 o = {f2bf(f0.x), f2bf(f0.y), f2bf(f0.z), f2bf(f0.w),
                 f2bf(f1.x), f2bf(f1.y), f2bf(f1.z), f2bf(f1.w)};
      *(u16x8*)&hdst[i] = o;
    }
    return;
  }
  __shared__ unsigned short tile[64 * 65];
  const float* srcs[4] = {s0, s1, s2, s3};
  const float* src = srcs[blockIdx.z];
  unsigned short* dst = d + (size_t)blockIdx.z * 512 * 512;
  int n0 = blockIdx.x * 64, k0 = blockIdx.y * 64;
  int tx = tid & 63, ty = tid >> 6;
  #pragma unroll
  for (int i = 0; i < 16; ++i) {
    int k = ty * 16 + i;
    tile[k * 65 + tx] = f2bf(src[(k0 + k) * 512 + n0 + tx]);
  }
  __syncthreads();
  #pragma unroll
  for (int i = 0; i < 16; ++i) {
    int n = ty * 16 + i;
    dst[(n0 + n) * 512 + k0 + tx] = tile[tx * 65 + n];
  }
}

// -------- fused QKV GEMM (128x64 tile, 3 blocks/CU) + RMSNorm + RoPE --------
// grid (32, 24): y = gh in [0,24) -> mat = gh>>3 (Q/K/V), head = gh&7.
// Wave w owns rows [w*32, w*32+32) x all 64 cols (full row in-wave).
// Q,K out: (B,H,T,C). V out: (B,H,C,T).
__global__ __launch_bounds__(256) void qkv_fused(
    const unsigned short* __restrict__ Hb,     // (4096,512) bf16
    const unsigned short* __restrict__ WTall,  // (1536,512) bf16 [n][k]
    const float* __restrict__ qnw, const float* __restrict__ knw,
    const float* __restrict__ rcos, const float* __restrict__ rsin,
    unsigned short* __restrict__ Qw, unsigned short* __restrict__ Kw,
    unsigned short* __restrict__ Vw) {
  __shared__ alignas(16) unsigned short S[12288];   // 24 KB
  unsigned short* Al = S;            // [128*64] 16 chunks of 1024B
  unsigned short* Bl = S + 8192;     // [64*64]   8 chunks
  int tid = threadIdx.x;
  int wave = tid >> 6, lane = tid & 63;
  int ln = lane & 15, qd = lane >> 4;
  int m0 = blockIdx.x * 128;
  int gh = blockIdx.y;               // block-uniform head
  int n0 = gh * 64;

  f32x4 acc[2][4];
  #pragma unroll
  for (int mi = 0; mi < 2; ++mi)
    #pragma unroll
    for (int ni = 0; ni < 4; ++ni) acc[mi][ni] = f32x4{0.f, 0.f, 0.f, 0.f};

  for (int k0 = 0; k0 < 512; k0 += 64) {
    #pragma unroll
    for (int s = 0; s < 4; ++s) {    // A: 16 chunks
      int q = s * 4 + wave;
      int L = q * 64 + lane;
      int row = L >> 3;
      int cb = (L & 7) ^ (row & 7);
      GLD16(&Hb[(size_t)(m0 + row) * 512 + k0 + cb * 8], (char*)Al + q * 1024);
    }
    #pragma unroll
    for (int s = 0; s < 2; ++s) {    // B: 8 chunks
      int q = s * 4 + wave;
      int L = q * 64 + lane;
      int row = L >> 3;
      int cb = (L & 7) ^ (row & 7);
      GLD16(&WTall[(size_t)(n0 + row) * 512 + k0 + cb * 8], (char*)Bl + q * 1024);
    }
    __syncthreads();
    #pragma unroll
    for (int half = 0; half < 2; ++half) {
      s16x8 af[2], bfr[4];
      #pragma unroll
      for (int mi = 0; mi < 2; ++mi) {
        int ar = wave * 32 + mi * 16 + ln;
        int cbp = (qd + half * 4) ^ (ar & 7);
        af[mi] = *(const s16x8*)((const char*)Al + ar * 128 + cbp * 16);
      }
      #pragma unroll
      for (int ni = 0; ni < 4; ++ni) {
        int br = ni * 16 + ln;
        int cbp = (qd + half * 4) ^ (br & 7);
        bfr[ni] = *(const s16x8*)((const char*)Bl + br * 128 + cbp * 16);
      }
      #pragma unroll
      for (int mi = 0; mi < 2; ++mi)
        #pragma unroll
        for (int ni = 0; ni < 4; ++ni)
          acc[mi][ni] = __builtin_amdgcn_mfma_f32_16x16x32_bf16(
              af[mi], bfr[ni], acc[mi][ni], 0, 0, 0);
    }
    __syncthreads();   // final barrier also guards epilogue reuse of S
  }

  int mat = gh >> 3, head = gh & 7;
  const float* nw = (mat == 0) ? qnw : knw;
  bool do_rope = (mat < 2);
  int mrow0 = m0 + wave * 32;
  int b = mrow0 >> 11, tb = mrow0 & (Tt - 1);

  #pragma unroll
  for (int mi = 0; mi < 2; ++mi) {
    float vals[4][4];
    #pragma unroll
    for (int ni = 0; ni < 4; ++ni)
      #pragma unroll
      for (int r = 0; r < 4; ++r) vals[ni][r] = acc[mi][ni][r];

    if (do_rope) {
      #pragma unroll
      for (int r = 0; r < 4; ++r) {
        float ss = 0.f;
        #pragma unroll
        for (int ni = 0; ni < 4; ++ni) ss += vals[ni][r] * vals[ni][r];
        ss += __shfl_xor(ss, 1, 64);
        ss += __shfl_xor(ss, 2, 64);
        ss += __shfl_xor(ss, 4, 64);
        ss += __shfl_xor(ss, 8, 64);
        float nrm = rsqrtf(ss * (1.0f / 64.0f) + 1e-6f);
        #pragma unroll
        for (int ni = 0; ni < 4; ++ni) vals[ni][r] *= nrm;
      }
      #pragma unroll
      for (int ni = 0; ni < 4; ++ni) {
        float w = nw[ni * 16 + ln];
        #pragma unroll
        for (int r = 0; r < 4; ++r) vals[ni][r] *= w;
      }
      float res[4][4];
      #pragma unroll
      for (int r = 0; r < 4; ++r) {
        int t = tb + mi * 16 + qd * 4 + r;
        #pragma unroll
        for (int ni = 0; ni < 4; ++ni) {
          int c = ni * 16 + ln;
          float cs = rcos[t * 64 + c];
          float sn = rsin[t * 64 + c];
          float part = vals[ni ^ 2][r];
          float rot = (ni < 2) ? -part : part;
          res[ni][r] = vals[ni][r] * cs + rot * sn;
        }
      }
      #pragma unroll
      for (int ni = 0; ni < 4; ++ni)
        #pragma unroll
        for (int r = 0; r < 4; ++r) vals[ni][r] = res[ni][r];
    }

    if (mat < 2) {   // [t_local 32][c 64] pad 72, wave-private
      unsigned short* Wl = S + wave * 2304;
      #pragma unroll
      for (int ni = 0; ni < 4; ++ni)
        #pragma unroll
        for (int r = 0; r < 4; ++r)
          Wl[(mi * 16 + qd * 4 + r) * 72 + ni * 16 + ln] = f2bf(vals[ni][r]);
    } else {         // V: [c 64][t_local 32] pad 40
      unsigned short* Wl = S + wave * 2560;
      #pragma unroll
      for (int ni = 0; ni < 4; ++ni)
        #pragma unroll
        for (int r = 0; r < 4; ++r)
          Wl[(ni * 16 + ln) * 40 + mi * 16 + qd * 4 + r] = f2bf(vals[ni][r]);
    }
  }

  if (mat < 2) {
    unsigned short* Wl = S + wave * 2304;
    unsigned short* Og =
        ((mat == 0) ? Qw : Kw) + (((size_t)b * Hh + head) * Tt + tb) * 64;
    #pragma unroll
    for (int i = 0; i < 4; ++i) {    // 32 rows x 64 = 256 chunks
      int idx = i * 64 + lane;
      int rr = idx >> 3, cc = (idx & 7) * 8;
      *(u16x8*)&Og[rr * 64 + cc] = *(const u16x8*)&Wl[rr * 72 + cc];
    }
  } else {
    unsigned short* Wl = S + wave * 2560;
    unsigned short* Og = Vw + ((size_t)b * Hh + head) * 64 * 2048 + tb;
    #pragma unroll
    for (int i = 0; i < 4; ++i) {    // 64 c-rows x 32 t = 256 chunks
      int idx = i * 64 + lane;
      int rr = idx >> 2, cc = (idx & 3) * 8;
      *(u16x8*)&Og[(size_t)rr * 2048 + cc] = *(const u16x8*)&Wl[rr * 40 + cc];
    }
  }
}

// ---------- MFMA sliding-window attention: 64 queries / block ---------------
// Q,K: (B,H,T,C); V: (B,H,C,T). AO: (B,T,H,C).
__global__ __launch_bounds__(256) void attn_mfma(
    const unsigned short* __restrict__ Q,
    const unsigned short* __restrict__ K,
    const unsigned short* __restrict__ Vg,
    unsigned short* __restrict__ AO) {
  __shared__ alignas(16) unsigned short KP[192 * 72];  // K tile; then P[64][200]
  __shared__ alignas(16) unsigned short Vt[64 * 200];  // [c][kk]
  int tid = threadIdx.x;
  int wave = tid >> 6, lane = tid & 63;
  int ln = lane & 15, qd = lane >> 4;
  int t0 = blockIdx.x * 64, bh = blockIdx.y;
  int kb = t0 - 128;
  int q0 = wave * 16;

  const unsigned short* Kg = K + (size_t)bh * Tt * 64;
  const unsigned short* Vb = Vg + (size_t)bh * 64 * 2048;

  int srow = tid >> 2, scol = (tid & 3) * 16;
  #pragma unroll
  for (int p = 0; p < 3; ++p) {
    int row = p * 64 + srow;
    int kg = kb + row; if (kg < 0) kg = 0;
    const u16x8* gk = (const u16x8*)&Kg[(size_t)kg * 64 + scol];
    u16x8 k0v = gk[0], k1v = gk[1];
    *(u16x8*)&KP[row * 72 + scol] = k0v;
    *(u16x8*)&KP[row * 72 + scol + 8] = k1v;
  }
  #pragma unroll
  for (int j = 0; j < 3; ++j)
    #pragma unroll
    for (int it = 0; it < 2; ++it) {
      int idx = it * 256 + tid;
      int row = idx >> 3, ch = (idx & 7) * 8;
      u16x8 v = *(const u16x8*)&Vb[(size_t)row * 2048 + kb + j * 64 + ch];
      *(u16x8*)&Vt[row * 200 + j * 64 + ch] = v;
    }
  const unsigned short* Qg = Q + ((size_t)bh * Tt + t0 + q0) * 64;
  s16x8 aq0 = *(const s16x8*)&Qg[ln * 64 + qd * 8];
  s16x8 aq1 = *(const s16x8*)&Qg[ln * 64 + 32 + qd * 8];
  __syncthreads();

  f32x4 sf[12];
  #pragma unroll
  for (int nt = 0; nt < 12; ++nt) {
    s16x8 b0 = *(const s16x8*)&KP[(nt * 16 + ln) * 72 + qd * 8];
    s16x8 b1 = *(const s16x8*)&KP[(nt * 16 + ln) * 72 + 32 + qd * 8];
    f32x4 a = {0.f, 0.f, 0.f, 0.f};
    a = __builtin_amdgcn_mfma_f32_16x16x32_bf16(aq0, b0, a, 0, 0, 0);
    a = __builtin_amdgcn_mfma_f32_16x16x32_bf16(aq1, b1, a, 0, 0, 0);
    sf[nt] = a;
  }
  __syncthreads();

  unsigned short* Pl = KP;
  int ok0 = (t0 < 128) ? (128 - t0) : 0;
  #pragma unroll
  for (int r = 0; r < 4; ++r) {
    int lq = q0 + qd * 4 + r;
    float mx = -INFINITY;
    #pragma unroll
    for (int nt = 0; nt < 12; ++nt) {
      int kk = nt * 16 + ln;
      bool valid = (kk > lq) && (kk <= lq + 128) && (kk >= ok0);
      float s = valid ? sf[nt][r] * 0.125f : -INFINITY;
      sf[nt][r] = s;
      mx = fmaxf(mx, s);
    }
    mx = fmaxf(mx, __shfl_xor(mx, 1, 64));
    mx = fmaxf(mx, __shfl_xor(mx, 2, 64));
    mx = fmaxf(mx, __shfl_xor(mx, 4, 64));
    mx = fmaxf(mx, __shfl_xor(mx, 8, 64));
    float sum = 0.f;
    #pragma unroll
    for (int nt = 0; nt < 12; ++nt) {
      float e = __expf(sf[nt][r] - mx);
      sf[nt][r] = e;
      sum += e;
    }
    sum += __shfl_xor(sum, 1, 64);
    sum += __shfl_xor(sum, 2, 64);
    sum += __shfl_xor(sum, 4, 64);
    sum += __shfl_xor(sum, 8, 64);
    float inv = 1.0f / sum;
    #pragma unroll
    for (int nt = 0; nt < 12; ++nt)
      Pl[lq * 200 + nt * 16 + ln] = f2bf(sf[nt][r] * inv);
  }

  f32x4 oa[4] = {f32x4{0,0,0,0}, f32x4{0,0,0,0}, f32x4{0,0,0,0}, f32x4{0,0,0,0}};
  #pragma unroll
  for (int s = 0; s < 6; ++s) {
    s16x8 ap = *(const s16x8*)&Pl[(q0 + ln) * 200 + s * 32 + qd * 8];
    #pragma unroll
    for (int nt = 0; nt < 4; ++nt) {
      s16x8 bv = *(const s16x8*)&Vt[(nt * 16 + ln) * 200 + s * 32 + qd * 8];
      oa[nt] = __builtin_amdgcn_mfma_f32_16x16x32_bf16(ap, bv, oa[nt], 0, 0, 0);
    }
  }

  unsigned short* Ow = KP + q0 * 200;
  #pragma unroll
  for (int ni = 0; ni < 4; ++ni)
    #pragma unroll
    for (int r = 0; r < 4; ++r)
      Ow[(qd * 4 + r) * 72 + ni * 16 + ln] = f2bf(oa[ni][r]);
  int b = bh >> 3, h = bh & 7;
  #pragma unroll
  for (int i = 0; i < 2; ++i) {
    int idx = i * 64 + lane;
    int rr = idx >> 3, cc = (idx & 7) * 8;
    *(u16x8*)&AO[((size_t)(b * Tt + t0 + q0 + rr) * Hh + h) * 64 + cc] =
        *(const u16x8*)&Ow[rr * 72 + cc];
  }
}

// ------------- output GEMM (64x64 tile, 2 blocks/CU): AO @ W_o -> f32 -------
__global__ __launch_bounds__(256) void out_gemm(
    const unsigned short* __restrict__ Am,  // (4096,512) bf16
    const unsigned short* __restrict__ WT,  // (512,512) bf16 [n][k]
    float* __restrict__ Out) {              // (4096,512) f32
  __shared__ alignas(16) unsigned short Al[64 * 64];
  __shared__ alignas(16) unsigned short Bl[64 * 64];
  int tid = threadIdx.x;
  int wave = tid >> 6, lane = tid & 63;
  int ln = lane & 15, qd = lane >> 4;
  int wm = wave >> 1, wn = wave & 1;
  int m0 = blockIdx.x * 64, n0 = blockIdx.y * 64;

  f32x4 acc[2][2];
  #pragma unroll
  for (int mi = 0; mi < 2; ++mi)
    #pragma unroll
    for (int ni = 0; ni < 2; ++ni) acc[mi][ni] = f32x4{0.f, 0.f, 0.f, 0.f};

  for (int k0 = 0; k0 < 512; k0 += 64) {
    #pragma unroll
    for (int s = 0; s < 2; ++s) {
      int q = s * 4 + wave;
      int L = q * 64 + lane;
      int row = L >> 3;
      int cb = (L & 7) ^ (row & 7);
      GLD16(&Am[(size_t)(m0 + row) * 512 + k0 + cb * 8], (char*)Al + q * 1024);
      GLD16(&WT[(size_t)(n0 + row) * 512 + k0 + cb * 8], (char*)Bl + q * 1024);
    }
    __syncthreads();
    #pragma unroll
    for (int half = 0; half < 2; ++half) {
      s16x8 af[2], bfr[2];
      #pragma unroll
      for (int mi = 0; mi < 2; ++mi) {
        int ar = wm * 32 + mi * 16 + ln;
        int cbp = (qd + half * 4) ^ (ar & 7);
        af[mi] = *(const s16x8*)((const char*)Al + ar * 128 + cbp * 16);
      }
      #pragma unroll
      for (int ni = 0; ni < 2; ++ni) {
        int br = wn * 32 + ni * 16 + ln;
        int cbp = (qd + half * 4) ^ (br & 7);
        bfr[ni] = *(const s16x8*)((const char*)Bl + br * 128 + cbp * 16);
      }
      #pragma unroll
      for (int mi = 0; mi < 2; ++mi)
        #pragma unroll
        for (int ni = 0; ni < 2; ++ni)
          acc[mi][ni] = __builtin_amdgcn_mfma_f32_16x16x32_bf16(
              af[mi], bfr[ni], acc[mi][ni], 0, 0, 0);
    }
    __syncthreads();
  }

  #pragma unroll
  for (int mi = 0; mi < 2; ++mi)
    #pragma unroll
    for (int r = 0; r < 4; ++r) {
      int row = m0 + wm * 32 + mi * 16 + qd * 4 + r;
      #pragma unroll
      for (int ni = 0; ni < 2; ++ni)
        Out[(size_t)row * 512 + n0 + wn * 32 + ni * 16 + ln] = acc[mi][ni][r];
    }
}

extern "C" void kernel_launch(void* const* d_in, const int* in_sizes, int n_in,
                              void* d_out, int out_size, void* d_ws, size_t ws_size,
                              hipStream_t stream) {
  const float* h   = (const float*)d_in[0];
  const float* rc  = (const float*)d_in[1];
  const float* rs  = (const float*)d_in[2];
  const float* Wq  = (const float*)d_in[3];
  const float* Wk  = (const float*)d_in[4];
  const float* Wv  = (const float*)d_in[5];
  const float* Wo  = (const float*)d_in[6];
  const float* qnw = (const float*)d_in[7];
  const float* knw = (const float*)d_in[8];

  unsigned short* ws    = (unsigned short*)d_ws;
  unsigned short* WTall = ws;                       // 1536*512 (q,k,v contiguous)
  unsigned short* WTo   = WTall + 1536 * 512;       // 512*512
  unsigned short* Hb    = WTo + 512 * 512;          // 4096*512 bf16
  unsigned short* Qw    = Hb + 2097152;             // (B,H,T,C)
  unsigned short* Kw    = Qw + 2097152;             // (B,H,T,C)
  unsigned short* Vw    = Kw + 2097152;             // (B,H,C,T)
  unsigned short* AOw   = Vw + 2097152;             // (B,T,H,C)

  prep_all<<<dim3(8, 8, 5), 256, 0, stream>>>(Wq, Wk, Wv, Wo, WTall, h, Hb);

  qkv_fused<<<dim3(32, 24), 256, 0, stream>>>(Hb, WTall, qnw, knw, rc, rs,
                                              Qw, Kw, Vw);

  attn_mfma<<<dim3(32, 16), 256, 0, stream>>>(Qw, Kw, Vw, AOw);

  out_gemm<<<dim3(64, 8), 256, 0, stream>>>(AOw, WTo, (float*)d_out);
}